// Round 8
// baseline (848.076 us; speedup 1.0000x reference)
//
#include <hip/hip_runtime.h>
#include <hip/hip_bf16.h>
#include <cstdint>

typedef float f32x4 __attribute__((ext_vector_type(4)));
typedef __bf16 bf16x8 __attribute__((ext_vector_type(8)));
typedef __bf16 bf16x4 __attribute__((ext_vector_type(4)));

#define HID 128

// Pack W [K][128] fp32 -> fragment-major bf16: Bf[ki][nf][lane][8]
__global__ void pack_b_frag(const float* __restrict__ W, __bf16* __restrict__ Bf, int kiters) {
    int idx = blockIdx.x * 256 + threadIdx.x;
    int total = kiters * 512;
    if (idx >= total) return;
    int lane = idx & 63;
    int nf = (idx >> 6) & 7;
    int ki = idx >> 9;
    int n = nf * 16 + (lane & 15);
    int kb = ki * 32 + ((lane >> 4) * 8);
    bf16x8 v;
#pragma unroll
    for (int j = 0; j < 8; ++j) v[j] = (__bf16)W[(size_t)(kb + j) * HID + n];
    *reinterpret_cast<bf16x8*>(Bf + (size_t)idx * 8) = v;
}

// m = relu(mel @ Wmel + bmel) — EXACT round-4 structure (519us best).
__global__ __launch_bounds__(256, 2) void gemm_mel2(
    const float* __restrict__ A0,
    const __bf16* __restrict__ Bf,
    const float* __restrict__ bias,
    float* __restrict__ out)
{
    const int tid = threadIdx.x;
    const int lane = tid & 63;
    const int wv = tid >> 6;
    const int row_base = blockIdx.x * 32;
    const int rif = lane & 15;
    const int kg = lane >> 4;

    __shared__ __align__(16) char ldsb[65536];

    f32x4 zero = {0.f, 0.f, 0.f, 0.f};
    f32x4 acc[2][8];
#pragma unroll
    for (int i = 0; i < 2; ++i)
#pragma unroll
        for (int j = 0; j < 8; ++j) acc[i][j] = zero;

    const bf16x8* __restrict__ BfV = reinterpret_cast<const bf16x8*>(Bf);

    f32x4 st[16];

    auto stage_load = [&](int s) {
#pragma unroll
        for (int j = 0; j < 16; ++j) {
            int seg = wv * 16 + j;
            int row = seg >> 1, half = seg & 1;
            const float* gp = A0 + (size_t)(row_base + row) * 16384 + s * 512 + half * 256 + (lane << 2);
            st[j] = __builtin_nontemporal_load(reinterpret_cast<const f32x4*>(gp));
        }
    };
    auto stage_write = [&](int buf) {
#pragma unroll
        for (int j = 0; j < 16; ++j) {
            int seg = wv * 16 + j;
            int row = seg >> 1, half = seg & 1;
            int byte = row * 1024 + ((half * 512 + lane * 8) ^ ((row & 7) << 4)) + buf * 32768;
            bf16x4 v;
            v[0] = (__bf16)st[j][0]; v[1] = (__bf16)st[j][1];
            v[2] = (__bf16)st[j][2]; v[3] = (__bf16)st[j][3];
            *reinterpret_cast<bf16x4*>(ldsb + byte) = v;
        }
    };
    auto compute2 = [&](int cur, int s, int kt0) {
#pragma unroll
        for (int kt = kt0; kt < kt0 + 2; ++kt) {
            bf16x8 af[2];
#pragma unroll
            for (int mi = 0; mi < 2; ++mi) {
                int row = mi * 16 + rif;
                int byte = row * 1024 + ((wv * 256 + kt * 64 + kg * 16) ^ ((rif & 7) << 4)) + cur * 32768;
                af[mi] = *reinterpret_cast<const bf16x8*>(ldsb + byte);
            }
            int ki = s * 16 + wv * 4 + kt;
            const bf16x8* bp = BfV + (size_t)ki * 512 + lane;
#pragma unroll
            for (int nf = 0; nf < 8; ++nf) {
                bf16x8 b = bp[nf * 64];
                acc[0][nf] = __builtin_amdgcn_mfma_f32_16x16x32_bf16(af[0], b, acc[0][nf], 0, 0, 0);
                acc[1][nf] = __builtin_amdgcn_mfma_f32_16x16x32_bf16(af[1], b, acc[1][nf], 0, 0, 0);
            }
        }
    };

    stage_load(0);
    stage_write(0);
    for (int s = 0; s < 32; ++s) {
        int cur = s & 1;
        if (s + 1 < 32) stage_load(s + 1);
        __syncthreads();
        compute2(cur, s, 0);
        compute2(cur, s, 2);
        if (s + 1 < 32) stage_write(cur ^ 1);
    }

    __syncthreads();
    float* red = reinterpret_cast<float*>(ldsb);
#pragma unroll
    for (int mi = 0; mi < 2; ++mi)
#pragma unroll
        for (int nf = 0; nf < 8; ++nf)
#pragma unroll
            for (int j = 0; j < 4; ++j)
                red[(wv * 32 + mi * 16 + kg * 4 + j) * HID + nf * 16 + rif] = acc[mi][nf][j];
    __syncthreads();
#pragma unroll
    for (int p = 0; p < 16; ++p) {
        int idx = tid + p * 256;
        int r = idx >> 7, c = idx & 127;
        float v = red[r * HID + c] + red[(32 + r) * HID + c]
                + red[(64 + r) * HID + c] + red[(96 + r) * HID + c];
        v = fmaxf(v + bias[c], 0.f);
        out[(size_t)(row_base + r) * HID + c] = v;
    }
}

// Fused: x = relu([text|m] @ Wcat + bcat); h1 = x @ W1  — exact round-4 version
__global__ __launch_bounds__(256) void gemm_cat_h1(
    const float* __restrict__ A0,
    const float* __restrict__ A1,
    const __bf16* __restrict__ Bf2,
    const __bf16* __restrict__ Bf3,
    const float* __restrict__ bcat,
    float* __restrict__ h1)
{
    const int tid = threadIdx.x;
    const int lane = tid & 63;
    const int w = tid >> 6;
    const int row_base = blockIdx.x * 32;
    const int rif = lane & 15;
    const int kg = lane >> 4;

    f32x4 zero = {0.f, 0.f, 0.f, 0.f};
    f32x4 acc[2][8];
#pragma unroll
    for (int i = 0; i < 2; ++i)
#pragma unroll
        for (int j = 0; j < 8; ++j) acc[i][j] = zero;

    const bf16x8* __restrict__ Bf2V = reinterpret_cast<const bf16x8*>(Bf2);
    const int kstart = w * 224;

#pragma unroll
    for (int it = 0; it < 7; ++it) {
        const int k0 = kstart + it * 32;
        const int kc = k0 + kg * 8;
        bf16x8 af[2];
#pragma unroll
        for (int mi = 0; mi < 2; ++mi) {
            const int row = row_base + mi * 16 + rif;
            const float* ap;
            if (kc < 768) ap = A0 + (size_t)row * 768 + kc;
            else          ap = A1 + (size_t)row * HID + (kc - 768);
            const f32x4* apv = reinterpret_cast<const f32x4*>(ap);
            f32x4 v0 = apv[0];
            f32x4 v1 = apv[1];
            af[mi][0] = (__bf16)v0.x; af[mi][1] = (__bf16)v0.y;
            af[mi][2] = (__bf16)v0.z; af[mi][3] = (__bf16)v0.w;
            af[mi][4] = (__bf16)v1.x; af[mi][5] = (__bf16)v1.y;
            af[mi][6] = (__bf16)v1.z; af[mi][7] = (__bf16)v1.w;
        }
        const bf16x8* bp = Bf2V + (size_t)(k0 >> 5) * 512 + lane;
#pragma unroll
        for (int nf = 0; nf < 8; ++nf) {
            bf16x8 b = bp[nf * 64];
            acc[0][nf] = __builtin_amdgcn_mfma_f32_16x16x32_bf16(af[0], b, acc[0][nf], 0, 0, 0);
            acc[1][nf] = __builtin_amdgcn_mfma_f32_16x16x32_bf16(af[1], b, acc[1][nf], 0, 0, 0);
        }
    }

    __shared__ float red[4][32][HID];
    __shared__ __bf16 xs[32][136];

#pragma unroll
    for (int mi = 0; mi < 2; ++mi)
#pragma unroll
        for (int nf = 0; nf < 8; ++nf)
#pragma unroll
            for (int j = 0; j < 4; ++j)
                red[w][mi * 16 + kg * 4 + j][nf * 16 + rif] = acc[mi][nf][j];
    __syncthreads();
#pragma unroll
    for (int p = 0; p < 16; ++p) {
        int idx = tid + p * 256;
        int r = idx >> 7, c = idx & 127;
        float v = red[0][r][c] + red[1][r][c] + red[2][r][c] + red[3][r][c];
        v = fmaxf(v + bcat[c], 0.f);
        xs[r][c] = (__bf16)v;
    }
    __syncthreads();

    f32x4 acc2[2][8];
#pragma unroll
    for (int i = 0; i < 2; ++i)
#pragma unroll
        for (int j = 0; j < 8; ++j) acc2[i][j] = zero;

    {
        const int k0 = w * 32;
        bf16x8 af[2];
#pragma unroll
        for (int mi = 0; mi < 2; ++mi)
            af[mi] = *reinterpret_cast<const bf16x8*>(&xs[mi * 16 + rif][k0 + kg * 8]);
        const bf16x8* bp = reinterpret_cast<const bf16x8*>(Bf3) + (size_t)w * 512 + lane;
#pragma unroll
        for (int nf = 0; nf < 8; ++nf) {
            bf16x8 b = bp[nf * 64];
            acc2[0][nf] = __builtin_amdgcn_mfma_f32_16x16x32_bf16(af[0], b, acc2[0][nf], 0, 0, 0);
            acc2[1][nf] = __builtin_amdgcn_mfma_f32_16x16x32_bf16(af[1], b, acc2[1][nf], 0, 0, 0);
        }
    }

#pragma unroll
    for (int mi = 0; mi < 2; ++mi)
#pragma unroll
        for (int nf = 0; nf < 8; ++nf)
#pragma unroll
            for (int j = 0; j < 4; ++j)
                red[w][mi * 16 + kg * 4 + j][nf * 16 + rif] = acc2[mi][nf][j];
    __syncthreads();
#pragma unroll
    for (int p = 0; p < 16; ++p) {
        int idx = tid + p * 256;
        int r = idx >> 7, c = idx & 127;
        float v = red[0][r][c] + red[1][r][c] + red[2][r][c] + red[3][r][c];
        h1[(size_t)(row_base + r) * HID + c] = v;
    }
}

__global__ void count_dst(const int* __restrict__ dst, int* __restrict__ cnt, int E) {
    int e = blockIdx.x * 256 + threadIdx.x;
    if (e < E) atomicAdd(&cnt[dst[e]], 1);
}

__global__ __launch_bounds__(1024) void scan_block(const int* __restrict__ cnt,
    int* __restrict__ offs, float* __restrict__ dinv, int n) {
    int tid = threadIdx.x;
    int CH = (n + 1023) >> 10;
    int s0 = tid * CH;
    int s1 = min(s0 + CH, n);
    int sum = 0;
    for (int i = s0; i < s1; ++i) sum += cnt[i];
    int lane = tid & 63, wv = tid >> 6;
    int s = sum;
#pragma unroll
    for (int off = 1; off < 64; off <<= 1) {
        int t = __shfl_up(s, off);
        if (lane >= off) s += t;
    }
    __shared__ int wsum[16];
    __shared__ int wbase[16];
    if (lane == 63) wsum[wv] = s;
    __syncthreads();
    if (tid == 0) {
        int a = 0;
#pragma unroll
        for (int k = 0; k < 16; ++k) { wbase[k] = a; a += wsum[k]; }
    }
    __syncthreads();
    int run = wbase[wv] + (s - sum);
    for (int i = s0; i < s1; ++i) {
        int v = cnt[i];
        offs[i] = run;
        dinv[i] = rsqrtf((float)(v + 1));
        run += v;
    }
}

__global__ void fill_csr(const int* __restrict__ src, const int* __restrict__ dst,
                         const int* __restrict__ offs, int* __restrict__ fill,
                         int* __restrict__ srcs, int E) {
    int e = blockIdx.x * 256 + threadIdx.x;
    if (e >= E) return;
    int d = dst[e];
    int p = offs[d] + atomicAdd(&fill[d], 1);
    srcs[p] = src[e];
}

__global__ __launch_bounds__(128) void agg_h_w2(const float* __restrict__ h,
    const float* __restrict__ dinv, const int* __restrict__ offs,
    const int* __restrict__ cnt, const int* __restrict__ srcs,
    const float* __restrict__ b1, const float* __restrict__ W2,
    float* __restrict__ h2, int n) {
    int i = blockIdx.x;
    int c = threadIdx.x;
    float di = dinv[i];
    float acc = h[(size_t)i * HID + c] * di;
    int o = offs[i], e = cnt[i];
    int t = 0;
    for (; t + 4 <= e; t += 4) {
        int a0 = srcs[o + t], a1 = srcs[o + t + 1], a2 = srcs[o + t + 2], a3 = srcs[o + t + 3];
        float d0 = dinv[a0], d1 = dinv[a1], d2 = dinv[a2], d3 = dinv[a3];
        float v0 = h[(size_t)a0 * HID + c], v1 = h[(size_t)a1 * HID + c];
        float v2 = h[(size_t)a2 * HID + c], v3 = h[(size_t)a3 * HID + c];
        acc += v0 * d0 + v1 * d1 + v2 * d2 + v3 * d3;
    }
    for (; t < e; ++t) {
        int s = srcs[o + t];
        acc += h[(size_t)s * HID + c] * dinv[s];
    }
    float yb = fmaxf(acc * di + b1[c], 0.f);
    float4 wr = *reinterpret_cast<const float4*>(W2 + c * 4);
    float p0 = yb * wr.x, p1 = yb * wr.y, p2 = yb * wr.z, p3 = yb * wr.w;
#pragma unroll
    for (int off = 32; off; off >>= 1) {
        p0 += __shfl_down(p0, off);
        p1 += __shfl_down(p1, off);
        p2 += __shfl_down(p2, off);
        p3 += __shfl_down(p3, off);
    }
    __shared__ float red[2][4];
    if ((c & 63) == 0) {
        int wv = c >> 6;
        red[wv][0] = p0; red[wv][1] = p1; red[wv][2] = p2; red[wv][3] = p3;
    }
    __syncthreads();
    if (c < 4) h2[(size_t)i * 4 + c] = red[0][c] + red[1][c];
}

__global__ void agg4(const float* __restrict__ h2, const float* __restrict__ dinv,
                     const int* __restrict__ offs, const int* __restrict__ cnt,
                     const int* __restrict__ srcs, const float* __restrict__ b2,
                     float* __restrict__ out, int n) {
    int gid = blockIdx.x * 256 + threadIdx.x;
    int i = gid >> 2;
    int c = gid & 3;
    if (i >= n) return;
    float di = dinv[i];
    float acc = h2[(size_t)i * 4 + c] * di;
    int o = offs[i], e = cnt[i];
    int t = 0;
    for (; t + 4 <= e; t += 4) {
        int a0 = srcs[o + t], a1 = srcs[o + t + 1], a2 = srcs[o + t + 2], a3 = srcs[o + t + 3];
        float v0 = h2[(size_t)a0 * 4 + c] * dinv[a0];
        float v1 = h2[(size_t)a1 * 4 + c] * dinv[a1];
        float v2 = h2[(size_t)a2 * 4 + c] * dinv[a2];
        float v3 = h2[(size_t)a3 * 4 + c] * dinv[a3];
        acc += v0 + v1 + v2 + v3;
    }
    for (; t < e; ++t) {
        int s = srcs[o + t];
        acc += h2[(size_t)s * 4 + c] * dinv[s];
    }
    out[(size_t)i * 4 + c] = acc * di + b2[c];
}

extern "C" void kernel_launch(void* const* d_in, const int* in_sizes, int n_in,
                              void* d_out, int out_size, void* d_ws, size_t ws_size,
                              hipStream_t stream) {
    const float* text = (const float*)d_in[0];
    const float* mel  = (const float*)d_in[1];
    const int*   ei   = (const int*)d_in[2];
    const float* Wmel = (const float*)d_in[3];
    const float* bmel = (const float*)d_in[4];
    const float* Wcat = (const float*)d_in[5];
    const float* bcat = (const float*)d_in[6];
    const float* W1   = (const float*)d_in[7];
    const float* b1   = (const float*)d_in[8];
    const float* W2   = (const float*)d_in[9];
    const float* b2   = (const float*)d_in[10];
    float* out = (float*)d_out;

    const int n = in_sizes[0] / 768;   // 20000
    const int E = in_sizes[2] / 2;     // 640000
    const int Kmel = 16384;
    const int Kcat = 896;

    char* ws = (char*)d_ws;
    size_t off = 0;
    auto alloc = [&](size_t bytes) {
        void* p = ws + off;
        off += (bytes + 255) & ~(size_t)255;
        return p;
    };
    __bf16* Bf1 = (__bf16*)alloc((size_t)Kmel * HID * 2);
    __bf16* Bf2 = (__bf16*)alloc((size_t)Kcat * HID * 2);
    __bf16* Bf3 = (__bf16*)alloc((size_t)HID * HID * 2);
    float* m    = (float*)alloc((size_t)n * HID * 4);
    float* h1   = (float*)alloc((size_t)n * HID * 4);
    float* h2   = (float*)alloc((size_t)n * 4 * 4);
    int* cnt    = (int*)alloc((size_t)n * 4);
    int* offs   = (int*)alloc((size_t)n * 4);
    int* fill   = (int*)alloc((size_t)n * 4);
    float* dinv = (float*)alloc((size_t)n * 4);
    int* srcs   = (int*)alloc((size_t)E * 4);
    float* m_dummy = (float*)alloc((size_t)n * HID * 4);   // MEASUREMENT: duplicate mel target
    (void)ws_size; (void)n_in; (void)out_size;

    const int* srcI = ei;
    const int* dstI = ei + E;

    // ---- degrees + CSR ----
    (void)hipMemsetAsync(cnt, 0, n * 4, stream);
    (void)hipMemsetAsync(fill, 0, n * 4, stream);
    count_dst<<<(E + 255) / 256, 256, 0, stream>>>(dstI, cnt, E);
    scan_block<<<1, 1024, 0, stream>>>(cnt, offs, dinv, n);
    fill_csr<<<(E + 255) / 256, 256, 0, stream>>>(srcI, dstI, offs, fill, srcs, E);

    // ---- pack weights ----
    pack_b_frag<<<(Kmel / 32 * 512 + 255) / 256, 256, 0, stream>>>(Wmel, Bf1, Kmel / 32);
    pack_b_frag<<<(Kcat / 32 * 512 + 255) / 256, 256, 0, stream>>>(Wcat, Bf2, Kcat / 32);
    pack_b_frag<<<(HID / 32 * 512 + 255) / 256, 256, 0, stream>>>(W1, Bf3, HID / 32);

    const int gblk = n / 32;  // 625
    // m = relu(mel @ Wmel + bmel)  -- round-4 version (real output)
    gemm_mel2<<<gblk, 256, 0, stream>>>(mel, Bf1, bmel, m);
    // MEASUREMENT DISPATCH: identical mel GEMM into dummy buffer.
    // dur_us(this round) - 519 = true cost of gemm_mel2. Output unread.
    gemm_mel2<<<gblk, 256, 0, stream>>>(mel, Bf1, bmel, m_dummy);
    // x = relu([text|m] @ Wcat + bcat); h1 = x @ W1   (fused)
    gemm_cat_h1<<<gblk, 256, 0, stream>>>(text, m, Bf2, Bf3, bcat, h1);
    // h2 = relu(agg(h1)+b1) @ W2    (fused)
    agg_h_w2<<<n, 128, 0, stream>>>(h1, dinv, offs, cnt, srcs, b1, W2, h2, n);
    // out = agg(h2) + b2
    agg4<<<(n * 4 + 255) / 256, 256, 0, stream>>>(h2, dinv, offs, cnt, srcs, b2, out, n);
}

// Round 9
// 531.829 us; speedup vs baseline: 1.5946x; 1.5946x over previous
//
#include <hip/hip_runtime.h>
#include <hip/hip_bf16.h>
#include <cstdint>

typedef float f32x4 __attribute__((ext_vector_type(4)));
typedef __bf16 bf16x8 __attribute__((ext_vector_type(8)));
typedef __bf16 bf16x4 __attribute__((ext_vector_type(4)));

#define HID 128

// Pack W [K][128] fp32 -> fragment-major bf16: Bf[ki][nf][lane][8]
__global__ void pack_b_frag(const float* __restrict__ W, __bf16* __restrict__ Bf, int kiters) {
    int idx = blockIdx.x * 256 + threadIdx.x;
    int total = kiters * 512;
    if (idx >= total) return;
    int lane = idx & 63;
    int nf = (idx >> 6) & 7;
    int ki = idx >> 9;
    int n = nf * 16 + (lane & 15);
    int kb = ki * 32 + ((lane >> 4) * 8);
    bf16x8 v;
#pragma unroll
    for (int j = 0; j < 8; ++j) v[j] = (__bf16)W[(size_t)(kb + j) * HID + n];
    *reinterpret_cast<bf16x8*>(Bf + (size_t)idx * 8) = v;
}

// m = relu(mel @ Wmel + bmel). r4 structure with ONE change: the A-prefetch for
// step s+1 is issued in 4 chunks interleaved at the top of each kt-group inside
// compute, instead of in one burst before the barrier. Forced vmcnt drains from
// B-waits then interleave with chunk issues -> A-loads stay outstanding through
// nearly the whole step -> HBM duty up from ~60%.
__global__ __launch_bounds__(256, 2) void gemm_mel6(
    const float* __restrict__ A0,
    const __bf16* __restrict__ Bf,
    const float* __restrict__ bias,
    float* __restrict__ out)
{
    const int tid = threadIdx.x;
    const int lane = tid & 63;
    const int wv = tid >> 6;
    const int row_base = blockIdx.x * 32;
    const int rif = lane & 15;
    const int kg = lane >> 4;

    __shared__ __align__(16) char ldsb[65536];

    f32x4 zero = {0.f, 0.f, 0.f, 0.f};
    f32x4 acc[2][8];
#pragma unroll
    for (int i = 0; i < 2; ++i)
#pragma unroll
        for (int j = 0; j < 8; ++j) acc[i][j] = zero;

    const bf16x8* __restrict__ BfV = reinterpret_cast<const bf16x8*>(Bf);

    f32x4 st[16];

    auto load_chunk = [&](int s, int j0) {
#pragma unroll
        for (int j = j0; j < j0 + 4; ++j) {
            int seg = wv * 16 + j;
            int row = seg >> 1, half = seg & 1;
            const float* gp = A0 + (size_t)(row_base + row) * 16384 + s * 512 + half * 256 + (lane << 2);
            st[j] = __builtin_nontemporal_load(reinterpret_cast<const f32x4*>(gp));
        }
    };
    auto stage_write = [&](int buf) {
#pragma unroll
        for (int j = 0; j < 16; ++j) {
            int seg = wv * 16 + j;
            int row = seg >> 1, half = seg & 1;
            int byte = row * 1024 + ((half * 512 + lane * 8) ^ ((row & 7) << 4)) + buf * 32768;
            bf16x4 v;
            v[0] = (__bf16)st[j][0]; v[1] = (__bf16)st[j][1];
            v[2] = (__bf16)st[j][2]; v[3] = (__bf16)st[j][3];
            *reinterpret_cast<bf16x4*>(ldsb + byte) = v;
        }
    };
    auto compute_kt = [&](int cur, int s, int kt) {
        bf16x8 af[2];
#pragma unroll
        for (int mi = 0; mi < 2; ++mi) {
            int row = mi * 16 + rif;
            int byte = row * 1024 + ((wv * 256 + kt * 64 + kg * 16) ^ ((rif & 7) << 4)) + cur * 32768;
            af[mi] = *reinterpret_cast<const bf16x8*>(ldsb + byte);
        }
        int ki = s * 16 + wv * 4 + kt;
        const bf16x8* bp = BfV + (size_t)ki * 512 + lane;
#pragma unroll
        for (int nf = 0; nf < 8; ++nf) {
            bf16x8 b = bp[nf * 64];
            acc[0][nf] = __builtin_amdgcn_mfma_f32_16x16x32_bf16(af[0], b, acc[0][nf], 0, 0, 0);
            acc[1][nf] = __builtin_amdgcn_mfma_f32_16x16x32_bf16(af[1], b, acc[1][nf], 0, 0, 0);
        }
    };

    // prologue: stage step 0
    load_chunk(0, 0); load_chunk(0, 4); load_chunk(0, 8); load_chunk(0, 12);
    stage_write(0);
    for (int s = 0; s < 32; ++s) {
        int cur = s & 1;
        __syncthreads();                 // buf[cur] writes visible
        bool pf = (s + 1 < 32);
        if (pf) load_chunk(s + 1, 0);
        compute_kt(cur, s, 0);
        if (pf) load_chunk(s + 1, 4);
        compute_kt(cur, s, 1);
        if (pf) load_chunk(s + 1, 8);
        compute_kt(cur, s, 2);
        if (pf) load_chunk(s + 1, 12);
        compute_kt(cur, s, 3);
        if (pf) stage_write(cur ^ 1);    // waits the chunks; disjoint rows per wave
    }

    __syncthreads();
    float* red = reinterpret_cast<float*>(ldsb);
#pragma unroll
    for (int mi = 0; mi < 2; ++mi)
#pragma unroll
        for (int nf = 0; nf < 8; ++nf)
#pragma unroll
            for (int j = 0; j < 4; ++j)
                red[(wv * 32 + mi * 16 + kg * 4 + j) * HID + nf * 16 + rif] = acc[mi][nf][j];
    __syncthreads();
#pragma unroll
    for (int p = 0; p < 16; ++p) {
        int idx = tid + p * 256;
        int r = idx >> 7, c = idx & 127;
        float v = red[r * HID + c] + red[(32 + r) * HID + c]
                + red[(64 + r) * HID + c] + red[(96 + r) * HID + c];
        v = fmaxf(v + bias[c], 0.f);
        out[(size_t)(row_base + r) * HID + c] = v;
    }
}

// Fused: x = relu([text|m] @ Wcat + bcat); h1 = x @ W1  — exact round-4 version
__global__ __launch_bounds__(256) void gemm_cat_h1(
    const float* __restrict__ A0,
    const float* __restrict__ A1,
    const __bf16* __restrict__ Bf2,
    const __bf16* __restrict__ Bf3,
    const float* __restrict__ bcat,
    float* __restrict__ h1)
{
    const int tid = threadIdx.x;
    const int lane = tid & 63;
    const int w = tid >> 6;
    const int row_base = blockIdx.x * 32;
    const int rif = lane & 15;
    const int kg = lane >> 4;

    f32x4 zero = {0.f, 0.f, 0.f, 0.f};
    f32x4 acc[2][8];
#pragma unroll
    for (int i = 0; i < 2; ++i)
#pragma unroll
        for (int j = 0; j < 8; ++j) acc[i][j] = zero;

    const bf16x8* __restrict__ Bf2V = reinterpret_cast<const bf16x8*>(Bf2);
    const int kstart = w * 224;

#pragma unroll
    for (int it = 0; it < 7; ++it) {
        const int k0 = kstart + it * 32;
        const int kc = k0 + kg * 8;
        bf16x8 af[2];
#pragma unroll
        for (int mi = 0; mi < 2; ++mi) {
            const int row = row_base + mi * 16 + rif;
            const float* ap;
            if (kc < 768) ap = A0 + (size_t)row * 768 + kc;
            else          ap = A1 + (size_t)row * HID + (kc - 768);
            const f32x4* apv = reinterpret_cast<const f32x4*>(ap);
            f32x4 v0 = apv[0];
            f32x4 v1 = apv[1];
            af[mi][0] = (__bf16)v0.x; af[mi][1] = (__bf16)v0.y;
            af[mi][2] = (__bf16)v0.z; af[mi][3] = (__bf16)v0.w;
            af[mi][4] = (__bf16)v1.x; af[mi][5] = (__bf16)v1.y;
            af[mi][6] = (__bf16)v1.z; af[mi][7] = (__bf16)v1.w;
        }
        const bf16x8* bp = Bf2V + (size_t)(k0 >> 5) * 512 + lane;
#pragma unroll
        for (int nf = 0; nf < 8; ++nf) {
            bf16x8 b = bp[nf * 64];
            acc[0][nf] = __builtin_amdgcn_mfma_f32_16x16x32_bf16(af[0], b, acc[0][nf], 0, 0, 0);
            acc[1][nf] = __builtin_amdgcn_mfma_f32_16x16x32_bf16(af[1], b, acc[1][nf], 0, 0, 0);
        }
    }

    __shared__ float red[4][32][HID];
    __shared__ __bf16 xs[32][136];

#pragma unroll
    for (int mi = 0; mi < 2; ++mi)
#pragma unroll
        for (int nf = 0; nf < 8; ++nf)
#pragma unroll
            for (int j = 0; j < 4; ++j)
                red[w][mi * 16 + kg * 4 + j][nf * 16 + rif] = acc[mi][nf][j];
    __syncthreads();
#pragma unroll
    for (int p = 0; p < 16; ++p) {
        int idx = tid + p * 256;
        int r = idx >> 7, c = idx & 127;
        float v = red[0][r][c] + red[1][r][c] + red[2][r][c] + red[3][r][c];
        v = fmaxf(v + bcat[c], 0.f);
        xs[r][c] = (__bf16)v;
    }
    __syncthreads();

    f32x4 acc2[2][8];
#pragma unroll
    for (int i = 0; i < 2; ++i)
#pragma unroll
        for (int j = 0; j < 8; ++j) acc2[i][j] = zero;

    {
        const int k0 = w * 32;
        bf16x8 af[2];
#pragma unroll
        for (int mi = 0; mi < 2; ++mi)
            af[mi] = *reinterpret_cast<const bf16x8*>(&xs[mi * 16 + rif][k0 + kg * 8]);
        const bf16x8* bp = reinterpret_cast<const bf16x8*>(Bf3) + (size_t)w * 512 + lane;
#pragma unroll
        for (int nf = 0; nf < 8; ++nf) {
            bf16x8 b = bp[nf * 64];
            acc2[0][nf] = __builtin_amdgcn_mfma_f32_16x16x32_bf16(af[0], b, acc2[0][nf], 0, 0, 0);
            acc2[1][nf] = __builtin_amdgcn_mfma_f32_16x16x32_bf16(af[1], b, acc2[1][nf], 0, 0, 0);
        }
    }

#pragma unroll
    for (int mi = 0; mi < 2; ++mi)
#pragma unroll
        for (int nf = 0; nf < 8; ++nf)
#pragma unroll
            for (int j = 0; j < 4; ++j)
                red[w][mi * 16 + kg * 4 + j][nf * 16 + rif] = acc2[mi][nf][j];
    __syncthreads();
#pragma unroll
    for (int p = 0; p < 16; ++p) {
        int idx = tid + p * 256;
        int r = idx >> 7, c = idx & 127;
        float v = red[0][r][c] + red[1][r][c] + red[2][r][c] + red[3][r][c];
        h1[(size_t)(row_base + r) * HID + c] = v;
    }
}

__global__ void count_dst(const int* __restrict__ dst, int* __restrict__ cnt, int E) {
    int e = blockIdx.x * 256 + threadIdx.x;
    if (e < E) atomicAdd(&cnt[dst[e]], 1);
}

__global__ __launch_bounds__(1024) void scan_block(const int* __restrict__ cnt,
    int* __restrict__ offs, float* __restrict__ dinv, int n) {
    int tid = threadIdx.x;
    int CH = (n + 1023) >> 10;
    int s0 = tid * CH;
    int s1 = min(s0 + CH, n);
    int sum = 0;
    for (int i = s0; i < s1; ++i) sum += cnt[i];
    int lane = tid & 63, wv = tid >> 6;
    int s = sum;
#pragma unroll
    for (int off = 1; off < 64; off <<= 1) {
        int t = __shfl_up(s, off);
        if (lane >= off) s += t;
    }
    __shared__ int wsum[16];
    __shared__ int wbase[16];
    if (lane == 63) wsum[wv] = s;
    __syncthreads();
    if (tid == 0) {
        int a = 0;
#pragma unroll
        for (int k = 0; k < 16; ++k) { wbase[k] = a; a += wsum[k]; }
    }
    __syncthreads();
    int run = wbase[wv] + (s - sum);
    for (int i = s0; i < s1; ++i) {
        int v = cnt[i];
        offs[i] = run;
        dinv[i] = rsqrtf((float)(v + 1));
        run += v;
    }
}

__global__ void fill_csr(const int* __restrict__ src, const int* __restrict__ dst,
                         const int* __restrict__ offs, int* __restrict__ fill,
                         int* __restrict__ srcs, int E) {
    int e = blockIdx.x * 256 + threadIdx.x;
    if (e >= E) return;
    int d = dst[e];
    int p = offs[d] + atomicAdd(&fill[d], 1);
    srcs[p] = src[e];
}

__global__ __launch_bounds__(128) void agg_h_w2(const float* __restrict__ h,
    const float* __restrict__ dinv, const int* __restrict__ offs,
    const int* __restrict__ cnt, const int* __restrict__ srcs,
    const float* __restrict__ b1, const float* __restrict__ W2,
    float* __restrict__ h2, int n) {
    int i = blockIdx.x;
    int c = threadIdx.x;
    float di = dinv[i];
    float acc = h[(size_t)i * HID + c] * di;
    int o = offs[i], e = cnt[i];
    int t = 0;
    for (; t + 4 <= e; t += 4) {
        int a0 = srcs[o + t], a1 = srcs[o + t + 1], a2 = srcs[o + t + 2], a3 = srcs[o + t + 3];
        float d0 = dinv[a0], d1 = dinv[a1], d2 = dinv[a2], d3 = dinv[a3];
        float v0 = h[(size_t)a0 * HID + c], v1 = h[(size_t)a1 * HID + c];
        float v2 = h[(size_t)a2 * HID + c], v3 = h[(size_t)a3 * HID + c];
        acc += v0 * d0 + v1 * d1 + v2 * d2 + v3 * d3;
    }
    for (; t < e; ++t) {
        int s = srcs[o + t];
        acc += h[(size_t)s * HID + c] * dinv[s];
    }
    float yb = fmaxf(acc * di + b1[c], 0.f);
    float4 wr = *reinterpret_cast<const float4*>(W2 + c * 4);
    float p0 = yb * wr.x, p1 = yb * wr.y, p2 = yb * wr.z, p3 = yb * wr.w;
#pragma unroll
    for (int off = 32; off; off >>= 1) {
        p0 += __shfl_down(p0, off);
        p1 += __shfl_down(p1, off);
        p2 += __shfl_down(p2, off);
        p3 += __shfl_down(p3, off);
    }
    __shared__ float red[2][4];
    if ((c & 63) == 0) {
        int wv = c >> 6;
        red[wv][0] = p0; red[wv][1] = p1; red[wv][2] = p2; red[wv][3] = p3;
    }
    __syncthreads();
    if (c < 4) h2[(size_t)i * 4 + c] = red[0][c] + red[1][c];
}

__global__ void agg4(const float* __restrict__ h2, const float* __restrict__ dinv,
                     const int* __restrict__ offs, const int* __restrict__ cnt,
                     const int* __restrict__ srcs, const float* __restrict__ b2,
                     float* __restrict__ out, int n) {
    int gid = blockIdx.x * 256 + threadIdx.x;
    int i = gid >> 2;
    int c = gid & 3;
    if (i >= n) return;
    float di = dinv[i];
    float acc = h2[(size_t)i * 4 + c] * di;
    int o = offs[i], e = cnt[i];
    int t = 0;
    for (; t + 4 <= e; t += 4) {
        int a0 = srcs[o + t], a1 = srcs[o + t + 1], a2 = srcs[o + t + 2], a3 = srcs[o + t + 3];
        float v0 = h2[(size_t)a0 * 4 + c] * dinv[a0];
        float v1 = h2[(size_t)a1 * 4 + c] * dinv[a1];
        float v2 = h2[(size_t)a2 * 4 + c] * dinv[a2];
        float v3 = h2[(size_t)a3 * 4 + c] * dinv[a3];
        acc += v0 + v1 + v2 + v3;
    }
    for (; t < e; ++t) {
        int s = srcs[o + t];
        acc += h2[(size_t)s * 4 + c] * dinv[s];
    }
    out[(size_t)i * 4 + c] = acc * di + b2[c];
}

extern "C" void kernel_launch(void* const* d_in, const int* in_sizes, int n_in,
                              void* d_out, int out_size, void* d_ws, size_t ws_size,
                              hipStream_t stream) {
    const float* text = (const float*)d_in[0];
    const float* mel  = (const float*)d_in[1];
    const int*   ei   = (const int*)d_in[2];
    const float* Wmel = (const float*)d_in[3];
    const float* bmel = (const float*)d_in[4];
    const float* Wcat = (const float*)d_in[5];
    const float* bcat = (const float*)d_in[6];
    const float* W1   = (const float*)d_in[7];
    const float* b1   = (const float*)d_in[8];
    const float* W2   = (const float*)d_in[9];
    const float* b2   = (const float*)d_in[10];
    float* out = (float*)d_out;

    const int n = in_sizes[0] / 768;   // 20000
    const int E = in_sizes[2] / 2;     // 640000
    const int Kmel = 16384;
    const int Kcat = 896;

    char* ws = (char*)d_ws;
    size_t off = 0;
    auto alloc = [&](size_t bytes) {
        void* p = ws + off;
        off += (bytes + 255) & ~(size_t)255;
        return p;
    };
    __bf16* Bf1 = (__bf16*)alloc((size_t)Kmel * HID * 2);
    __bf16* Bf2 = (__bf16*)alloc((size_t)Kcat * HID * 2);
    __bf16* Bf3 = (__bf16*)alloc((size_t)HID * HID * 2);
    float* m    = (float*)alloc((size_t)n * HID * 4);
    float* h1   = (float*)alloc((size_t)n * HID * 4);
    float* h2   = (float*)alloc((size_t)n * 4 * 4);
    int* cnt    = (int*)alloc((size_t)n * 4);
    int* offs   = (int*)alloc((size_t)n * 4);
    int* fill   = (int*)alloc((size_t)n * 4);
    float* dinv = (float*)alloc((size_t)n * 4);
    int* srcs   = (int*)alloc((size_t)E * 4);
    (void)ws_size; (void)n_in; (void)out_size;

    const int* srcI = ei;
    const int* dstI = ei + E;

    // ---- degrees + CSR ----
    (void)hipMemsetAsync(cnt, 0, n * 4, stream);
    (void)hipMemsetAsync(fill, 0, n * 4, stream);
    count_dst<<<(E + 255) / 256, 256, 0, stream>>>(dstI, cnt, E);
    scan_block<<<1, 1024, 0, stream>>>(cnt, offs, dinv, n);
    fill_csr<<<(E + 255) / 256, 256, 0, stream>>>(srcI, dstI, offs, fill, srcs, E);

    // ---- pack weights ----
    pack_b_frag<<<(Kmel / 32 * 512 + 255) / 256, 256, 0, stream>>>(Wmel, Bf1, Kmel / 32);
    pack_b_frag<<<(Kcat / 32 * 512 + 255) / 256, 256, 0, stream>>>(Wcat, Bf2, Kcat / 32);
    pack_b_frag<<<(HID / 32 * 512 + 255) / 256, 256, 0, stream>>>(W1, Bf3, HID / 32);

    const int gblk = n / 32;  // 625
    // m = relu(mel @ Wmel + bmel)  -- interleaved A-prefetch version
    gemm_mel6<<<gblk, 256, 0, stream>>>(mel, Bf1, bmel, m);
    // x = relu([text|m] @ Wcat + bcat); h1 = x @ W1   (fused)
    gemm_cat_h1<<<gblk, 256, 0, stream>>>(text, m, Bf2, Bf3, bcat, h1);
    // h2 = relu(agg(h1)+b1) @ W2    (fused)
    agg_h_w2<<<n, 128, 0, stream>>>(h1, dinv, offs, cnt, srcs, b1, W2, h2, n);
    // out = agg(h2) + b2
    agg4<<<(n * 4 + 255) / 256, 256, 0, stream>>>(h2, dinv, offs, cnt, srcs, b2, out, n);
}

// Round 10
// 468.411 us; speedup vs baseline: 1.8105x; 1.1354x over previous
//
#include <hip/hip_runtime.h>
#include <hip/hip_bf16.h>
#include <cstdint>

typedef float f32x4 __attribute__((ext_vector_type(4)));
typedef __bf16 bf16x8 __attribute__((ext_vector_type(8)));
typedef __bf16 bf16x4 __attribute__((ext_vector_type(4)));

#define HID 128

// Pack W [K][128] fp32 -> fragment-major bf16: Bf[ki][nf][lane][8]
__global__ void pack_b_frag(const float* __restrict__ W, __bf16* __restrict__ Bf, int kiters) {
    int idx = blockIdx.x * 256 + threadIdx.x;
    int total = kiters * 512;
    if (idx >= total) return;
    int lane = idx & 63;
    int nf = (idx >> 6) & 7;
    int ki = idx >> 9;
    int n = nf * 16 + (lane & 15);
    int kb = ki * 32 + ((lane >> 4) * 8);
    bf16x8 v;
#pragma unroll
    for (int j = 0; j < 8; ++j) v[j] = (__bf16)W[(size_t)(kb + j) * HID + n];
    *reinterpret_cast<bf16x8*>(Bf + (size_t)idx * 8) = v;
}

// mel GEMM, K-split x2: EXACT r4 inner loop; block (tile,half) computes the
// partial over K-half 'half' for 32 rows, writes f32 partial (no bias/relu).
// 1250 blocks -> per-CU max 5 vs mean 4.88 (2.5% imbalance vs 23% at 625/512).
// Half-major block order: first generation shares one 2MB B-half in L2.
__global__ __launch_bounds__(256, 2) void gemm_mel_ks(
    const float* __restrict__ A0,
    const __bf16* __restrict__ Bf,
    float* __restrict__ part)
{
    const int tid = threadIdx.x;
    const int lane = tid & 63;
    const int wv = tid >> 6;
    const int half = blockIdx.x >= 625 ? 1 : 0;
    const int row_base = (blockIdx.x - half * 625) * 32;
    const int rif = lane & 15;
    const int kg = lane >> 4;
    const int s0 = half * 16;

    __shared__ __align__(16) char ldsb[65536];

    f32x4 zero = {0.f, 0.f, 0.f, 0.f};
    f32x4 acc[2][8];
#pragma unroll
    for (int i = 0; i < 2; ++i)
#pragma unroll
        for (int j = 0; j < 8; ++j) acc[i][j] = zero;

    const bf16x8* __restrict__ BfV = reinterpret_cast<const bf16x8*>(Bf);

    f32x4 st[16];

    auto stage_load = [&](int s) {
#pragma unroll
        for (int j = 0; j < 16; ++j) {
            int seg = wv * 16 + j;
            int row = seg >> 1, halfseg = seg & 1;
            const float* gp = A0 + (size_t)(row_base + row) * 16384 + s * 512 + halfseg * 256 + (lane << 2);
            st[j] = __builtin_nontemporal_load(reinterpret_cast<const f32x4*>(gp));
        }
    };
    auto stage_write = [&](int buf) {
#pragma unroll
        for (int j = 0; j < 16; ++j) {
            int seg = wv * 16 + j;
            int row = seg >> 1, halfseg = seg & 1;
            int byte = row * 1024 + ((halfseg * 512 + lane * 8) ^ ((row & 7) << 4)) + buf * 32768;
            bf16x4 v;
            v[0] = (__bf16)st[j][0]; v[1] = (__bf16)st[j][1];
            v[2] = (__bf16)st[j][2]; v[3] = (__bf16)st[j][3];
            *reinterpret_cast<bf16x4*>(ldsb + byte) = v;
        }
    };
    auto compute2 = [&](int cur, int s, int kt0) {
#pragma unroll
        for (int kt = kt0; kt < kt0 + 2; ++kt) {
            bf16x8 af[2];
#pragma unroll
            for (int mi = 0; mi < 2; ++mi) {
                int row = mi * 16 + rif;
                int byte = row * 1024 + ((wv * 256 + kt * 64 + kg * 16) ^ ((rif & 7) << 4)) + cur * 32768;
                af[mi] = *reinterpret_cast<const bf16x8*>(ldsb + byte);
            }
            int ki = s * 16 + wv * 4 + kt;
            const bf16x8* bp = BfV + (size_t)ki * 512 + lane;
#pragma unroll
            for (int nf = 0; nf < 8; ++nf) {
                bf16x8 b = bp[nf * 64];
                acc[0][nf] = __builtin_amdgcn_mfma_f32_16x16x32_bf16(af[0], b, acc[0][nf], 0, 0, 0);
                acc[1][nf] = __builtin_amdgcn_mfma_f32_16x16x32_bf16(af[1], b, acc[1][nf], 0, 0, 0);
            }
        }
    };

    stage_load(s0);
    stage_write(0);
    for (int t = 0; t < 16; ++t) {
        int s = s0 + t;
        int cur = t & 1;
        if (t + 1 < 16) stage_load(s + 1);
        __syncthreads();
        compute2(cur, s, 0);
        compute2(cur, s, 2);
        if (t + 1 < 16) stage_write(cur ^ 1);
    }

    __syncthreads();
    float* red = reinterpret_cast<float*>(ldsb);
#pragma unroll
    for (int mi = 0; mi < 2; ++mi)
#pragma unroll
        for (int nf = 0; nf < 8; ++nf)
#pragma unroll
            for (int j = 0; j < 4; ++j)
                red[(wv * 32 + mi * 16 + kg * 4 + j) * HID + nf * 16 + rif] = acc[mi][nf][j];
    __syncthreads();
    float* pb = part + (size_t)half * 20000 * HID;
#pragma unroll
    for (int p = 0; p < 16; ++p) {
        int idx = tid + p * 256;
        int r = idx >> 7, c = idx & 127;
        float v = red[r * HID + c] + red[(32 + r) * HID + c]
                + red[(64 + r) * HID + c] + red[(96 + r) * HID + c];
        pb[(size_t)(row_base + r) * HID + c] = v;
    }
}

// m = relu(p0 + p1 + bias)   (vectorized f32x4; 640000 elements of f32x4)
__global__ void combine_m(const float* __restrict__ part, const float* __restrict__ bias,
                          float* __restrict__ m) {
    int idx = blockIdx.x * 256 + threadIdx.x;   // 0..639999
    const f32x4* p0 = reinterpret_cast<const f32x4*>(part);
    const f32x4* p1 = reinterpret_cast<const f32x4*>(part + (size_t)20000 * HID);
    f32x4 b = *reinterpret_cast<const f32x4*>(bias + (idx & 31) * 4);
    f32x4 v = p0[idx] + p1[idx] + b;
    f32x4 r;
    r.x = fmaxf(v.x, 0.f); r.y = fmaxf(v.y, 0.f);
    r.z = fmaxf(v.z, 0.f); r.w = fmaxf(v.w, 0.f);
    reinterpret_cast<f32x4*>(m)[idx] = r;
}

// Fused: x = relu([text|m] @ Wcat + bcat) (LDS-only); h1 = x @ W1 -> bf16
__global__ __launch_bounds__(256) void gemm_cat_h1(
    const float* __restrict__ A0,
    const float* __restrict__ A1,
    const __bf16* __restrict__ Bf2,
    const __bf16* __restrict__ Bf3,
    const float* __restrict__ bcat,
    __bf16* __restrict__ h1)
{
    const int tid = threadIdx.x;
    const int lane = tid & 63;
    const int w = tid >> 6;
    const int row_base = blockIdx.x * 32;
    const int rif = lane & 15;
    const int kg = lane >> 4;

    f32x4 zero = {0.f, 0.f, 0.f, 0.f};
    f32x4 acc[2][8];
#pragma unroll
    for (int i = 0; i < 2; ++i)
#pragma unroll
        for (int j = 0; j < 8; ++j) acc[i][j] = zero;

    const bf16x8* __restrict__ Bf2V = reinterpret_cast<const bf16x8*>(Bf2);
    const int kstart = w * 224;

#pragma unroll
    for (int it = 0; it < 7; ++it) {
        const int k0 = kstart + it * 32;
        const int kc = k0 + kg * 8;
        bf16x8 af[2];
#pragma unroll
        for (int mi = 0; mi < 2; ++mi) {
            const int row = row_base + mi * 16 + rif;
            const float* ap;
            if (kc < 768) ap = A0 + (size_t)row * 768 + kc;
            else          ap = A1 + (size_t)row * HID + (kc - 768);
            const f32x4* apv = reinterpret_cast<const f32x4*>(ap);
            f32x4 v0 = apv[0];
            f32x4 v1 = apv[1];
            af[mi][0] = (__bf16)v0.x; af[mi][1] = (__bf16)v0.y;
            af[mi][2] = (__bf16)v0.z; af[mi][3] = (__bf16)v0.w;
            af[mi][4] = (__bf16)v1.x; af[mi][5] = (__bf16)v1.y;
            af[mi][6] = (__bf16)v1.z; af[mi][7] = (__bf16)v1.w;
        }
        const bf16x8* bp = Bf2V + (size_t)(k0 >> 5) * 512 + lane;
#pragma unroll
        for (int nf = 0; nf < 8; ++nf) {
            bf16x8 b = bp[nf * 64];
            acc[0][nf] = __builtin_amdgcn_mfma_f32_16x16x32_bf16(af[0], b, acc[0][nf], 0, 0, 0);
            acc[1][nf] = __builtin_amdgcn_mfma_f32_16x16x32_bf16(af[1], b, acc[1][nf], 0, 0, 0);
        }
    }

    __shared__ float red[4][32][HID];
    __shared__ __bf16 xs[32][136];

#pragma unroll
    for (int mi = 0; mi < 2; ++mi)
#pragma unroll
        for (int nf = 0; nf < 8; ++nf)
#pragma unroll
            for (int j = 0; j < 4; ++j)
                red[w][mi * 16 + kg * 4 + j][nf * 16 + rif] = acc[mi][nf][j];
    __syncthreads();
#pragma unroll
    for (int p = 0; p < 16; ++p) {
        int idx = tid + p * 256;
        int r = idx >> 7, c = idx & 127;
        float v = red[0][r][c] + red[1][r][c] + red[2][r][c] + red[3][r][c];
        v = fmaxf(v + bcat[c], 0.f);
        xs[r][c] = (__bf16)v;
    }
    __syncthreads();

    f32x4 acc2[2][8];
#pragma unroll
    for (int i = 0; i < 2; ++i)
#pragma unroll
        for (int j = 0; j < 8; ++j) acc2[i][j] = zero;

    {
        const int k0 = w * 32;
        bf16x8 af[2];
#pragma unroll
        for (int mi = 0; mi < 2; ++mi)
            af[mi] = *reinterpret_cast<const bf16x8*>(&xs[mi * 16 + rif][k0 + kg * 8]);
        const bf16x8* bp = reinterpret_cast<const bf16x8*>(Bf3) + (size_t)w * 512 + lane;
#pragma unroll
        for (int nf = 0; nf < 8; ++nf) {
            bf16x8 b = bp[nf * 64];
            acc2[0][nf] = __builtin_amdgcn_mfma_f32_16x16x32_bf16(af[0], b, acc2[0][nf], 0, 0, 0);
            acc2[1][nf] = __builtin_amdgcn_mfma_f32_16x16x32_bf16(af[1], b, acc2[1][nf], 0, 0, 0);
        }
    }

#pragma unroll
    for (int mi = 0; mi < 2; ++mi)
#pragma unroll
        for (int nf = 0; nf < 8; ++nf)
#pragma unroll
            for (int j = 0; j < 4; ++j)
                red[w][mi * 16 + kg * 4 + j][nf * 16 + rif] = acc2[mi][nf][j];
    __syncthreads();
#pragma unroll
    for (int p = 0; p < 16; ++p) {
        int idx = tid + p * 256;
        int r = idx >> 7, c = idx & 127;
        float v = red[0][r][c] + red[1][r][c] + red[2][r][c] + red[3][r][c];
        h1[(size_t)(row_base + r) * HID + c] = (__bf16)v;
    }
}

__global__ void count_dst(const int* __restrict__ dst, int* __restrict__ cnt, int E) {
    int e = blockIdx.x * 256 + threadIdx.x;
    if (e < E) atomicAdd(&cnt[dst[e]], 1);
}

__global__ __launch_bounds__(1024) void scan_block(const int* __restrict__ cnt,
    int* __restrict__ offs, float* __restrict__ dinv, int n) {
    int tid = threadIdx.x;
    int CH = (n + 1023) >> 10;
    int s0 = tid * CH;
    int s1 = min(s0 + CH, n);
    int sum = 0;
    for (int i = s0; i < s1; ++i) sum += cnt[i];
    int lane = tid & 63, wv = tid >> 6;
    int s = sum;
#pragma unroll
    for (int off = 1; off < 64; off <<= 1) {
        int t = __shfl_up(s, off);
        if (lane >= off) s += t;
    }
    __shared__ int wsum[16];
    __shared__ int wbase[16];
    if (lane == 63) wsum[wv] = s;
    __syncthreads();
    if (tid == 0) {
        int a = 0;
#pragma unroll
        for (int k = 0; k < 16; ++k) { wbase[k] = a; a += wsum[k]; }
    }
    __syncthreads();
    int run = wbase[wv] + (s - sum);
    for (int i = s0; i < s1; ++i) {
        int v = cnt[i];
        offs[i] = run;
        dinv[i] = rsqrtf((float)(v + 1));
        run += v;
    }
}

__global__ void fill_csr(const int* __restrict__ src, const int* __restrict__ dst,
                         const int* __restrict__ offs, int* __restrict__ fill,
                         int* __restrict__ srcs, int E) {
    int e = blockIdx.x * 256 + threadIdx.x;
    if (e >= E) return;
    int d = dst[e];
    int p = offs[d] + atomicAdd(&fill[d], 1);
    srcs[p] = src[e];
}

// Fused: yb = relu(dinv_i*(sum_s h[s]*dinv[s] + dinv_i*h[i]) + b1); h2 = yb @ W2
// h is bf16: scattered gather traffic halved vs f32.
__global__ __launch_bounds__(128) void agg_h_w2(const __bf16* __restrict__ h,
    const float* __restrict__ dinv, const int* __restrict__ offs,
    const int* __restrict__ cnt, const int* __restrict__ srcs,
    const float* __restrict__ b1, const float* __restrict__ W2,
    float* __restrict__ h2, int n) {
    int i = blockIdx.x;
    int c = threadIdx.x;
    float di = dinv[i];
    float acc = (float)h[(size_t)i * HID + c] * di;
    int o = offs[i], e = cnt[i];
    int t = 0;
    for (; t + 4 <= e; t += 4) {
        int a0 = srcs[o + t], a1 = srcs[o + t + 1], a2 = srcs[o + t + 2], a3 = srcs[o + t + 3];
        float d0 = dinv[a0], d1 = dinv[a1], d2 = dinv[a2], d3 = dinv[a3];
        float v0 = (float)h[(size_t)a0 * HID + c], v1 = (float)h[(size_t)a1 * HID + c];
        float v2 = (float)h[(size_t)a2 * HID + c], v3 = (float)h[(size_t)a3 * HID + c];
        acc += v0 * d0 + v1 * d1 + v2 * d2 + v3 * d3;
    }
    for (; t < e; ++t) {
        int s = srcs[o + t];
        acc += (float)h[(size_t)s * HID + c] * dinv[s];
    }
    float yb = fmaxf(acc * di + b1[c], 0.f);
    float4 wr = *reinterpret_cast<const float4*>(W2 + c * 4);
    float p0 = yb * wr.x, p1 = yb * wr.y, p2 = yb * wr.z, p3 = yb * wr.w;
#pragma unroll
    for (int off = 32; off; off >>= 1) {
        p0 += __shfl_down(p0, off);
        p1 += __shfl_down(p1, off);
        p2 += __shfl_down(p2, off);
        p3 += __shfl_down(p3, off);
    }
    __shared__ float red[2][4];
    if ((c & 63) == 0) {
        int wv = c >> 6;
        red[wv][0] = p0; red[wv][1] = p1; red[wv][2] = p2; red[wv][3] = p3;
    }
    __syncthreads();
    if (c < 4) h2[(size_t)i * 4 + c] = red[0][c] + red[1][c];
}

__global__ void agg4(const float* __restrict__ h2, const float* __restrict__ dinv,
                     const int* __restrict__ offs, const int* __restrict__ cnt,
                     const int* __restrict__ srcs, const float* __restrict__ b2,
                     float* __restrict__ out, int n) {
    int gid = blockIdx.x * 256 + threadIdx.x;
    int i = gid >> 2;
    int c = gid & 3;
    if (i >= n) return;
    float di = dinv[i];
    float acc = h2[(size_t)i * 4 + c] * di;
    int o = offs[i], e = cnt[i];
    int t = 0;
    for (; t + 4 <= e; t += 4) {
        int a0 = srcs[o + t], a1 = srcs[o + t + 1], a2 = srcs[o + t + 2], a3 = srcs[o + t + 3];
        float v0 = h2[(size_t)a0 * 4 + c] * dinv[a0];
        float v1 = h2[(size_t)a1 * 4 + c] * dinv[a1];
        float v2 = h2[(size_t)a2 * 4 + c] * dinv[a2];
        float v3 = h2[(size_t)a3 * 4 + c] * dinv[a3];
        acc += v0 + v1 + v2 + v3;
    }
    for (; t < e; ++t) {
        int s = srcs[o + t];
        acc += h2[(size_t)s * 4 + c] * dinv[s];
    }
    out[(size_t)i * 4 + c] = acc * di + b2[c];
}

extern "C" void kernel_launch(void* const* d_in, const int* in_sizes, int n_in,
                              void* d_out, int out_size, void* d_ws, size_t ws_size,
                              hipStream_t stream) {
    const float* text = (const float*)d_in[0];
    const float* mel  = (const float*)d_in[1];
    const int*   ei   = (const int*)d_in[2];
    const float* Wmel = (const float*)d_in[3];
    const float* bmel = (const float*)d_in[4];
    const float* Wcat = (const float*)d_in[5];
    const float* bcat = (const float*)d_in[6];
    const float* W1   = (const float*)d_in[7];
    const float* b1   = (const float*)d_in[8];
    const float* W2   = (const float*)d_in[9];
    const float* b2   = (const float*)d_in[10];
    float* out = (float*)d_out;

    const int n = in_sizes[0] / 768;   // 20000
    const int E = in_sizes[2] / 2;     // 640000
    const int Kmel = 16384;
    const int Kcat = 896;

    char* ws = (char*)d_ws;
    size_t off = 0;
    auto alloc = [&](size_t bytes) {
        void* p = ws + off;
        off += (bytes + 255) & ~(size_t)255;
        return p;
    };
    __bf16* Bf1 = (__bf16*)alloc((size_t)Kmel * HID * 2);
    __bf16* Bf2 = (__bf16*)alloc((size_t)Kcat * HID * 2);
    __bf16* Bf3 = (__bf16*)alloc((size_t)HID * HID * 2);
    float* part = (float*)alloc((size_t)2 * n * HID * 4);
    float* m    = (float*)alloc((size_t)n * HID * 4);
    __bf16* h1  = (__bf16*)alloc((size_t)n * HID * 2);
    float* h2   = (float*)alloc((size_t)n * 4 * 4);
    int* cnt    = (int*)alloc((size_t)n * 4);
    int* offs   = (int*)alloc((size_t)n * 4);
    int* fill   = (int*)alloc((size_t)n * 4);
    float* dinv = (float*)alloc((size_t)n * 4);
    int* srcs   = (int*)alloc((size_t)E * 4);
    (void)ws_size; (void)n_in; (void)out_size;

    const int* srcI = ei;
    const int* dstI = ei + E;

    // ---- degrees + CSR ----
    (void)hipMemsetAsync(cnt, 0, n * 4, stream);
    (void)hipMemsetAsync(fill, 0, n * 4, stream);
    count_dst<<<(E + 255) / 256, 256, 0, stream>>>(dstI, cnt, E);
    scan_block<<<1, 1024, 0, stream>>>(cnt, offs, dinv, n);
    fill_csr<<<(E + 255) / 256, 256, 0, stream>>>(srcI, dstI, offs, fill, srcs, E);

    // ---- pack weights ----
    pack_b_frag<<<(Kmel / 32 * 512 + 255) / 256, 256, 0, stream>>>(Wmel, Bf1, Kmel / 32);
    pack_b_frag<<<(Kcat / 32 * 512 + 255) / 256, 256, 0, stream>>>(Wcat, Bf2, Kcat / 32);
    pack_b_frag<<<(HID / 32 * 512 + 255) / 256, 256, 0, stream>>>(W1, Bf3, HID / 32);

    // mel GEMM: K-split x2, 1250 half-K blocks (tail imbalance 23% -> 2.5%)
    gemm_mel_ks<<<1250, 256, 0, stream>>>(mel, Bf1, part);
    // m = relu(p0 + p1 + bmel)
    combine_m<<<(n * HID / 4) / 256, 256, 0, stream>>>(part, bmel, m);
    // x = relu([text|m] @ Wcat + bcat); h1 = x @ W1 -> bf16   (fused)
    gemm_cat_h1<<<n / 32, 256, 0, stream>>>(text, m, Bf2, Bf3, bcat, h1);
    // h2 = relu(agg(h1)+b1) @ W2    (fused)
    agg_h_w2<<<n, 128, 0, stream>>>(h1, dinv, offs, cnt, srcs, b1, W2, h2, n);
    // out = agg(h2) + b2
    agg4<<<(n * 4 + 255) / 256, 256, 0, stream>>>(h2, dinv, offs, cnt, srcs, b2, out, n);
}

// Round 11
// 466.408 us; speedup vs baseline: 1.8183x; 1.0043x over previous
//
#include <hip/hip_runtime.h>
#include <hip/hip_bf16.h>
#include <cstdint>

typedef float f32x4 __attribute__((ext_vector_type(4)));
typedef __bf16 bf16x8 __attribute__((ext_vector_type(8)));
typedef __bf16 bf16x4 __attribute__((ext_vector_type(4)));

#define HID 128

// Pack W [K][128] fp32 -> fragment-major bf16: Bf[ki][nf][lane][8]
__global__ void pack_b_frag(const float* __restrict__ W, __bf16* __restrict__ Bf, int kiters) {
    int idx = blockIdx.x * 256 + threadIdx.x;
    int total = kiters * 512;
    if (idx >= total) return;
    int lane = idx & 63;
    int nf = (idx >> 6) & 7;
    int ki = idx >> 9;
    int n = nf * 16 + (lane & 15);
    int kb = ki * 32 + ((lane >> 4) * 8);
    bf16x8 v;
#pragma unroll
    for (int j = 0; j < 8; ++j) v[j] = (__bf16)W[(size_t)(kb + j) * HID + n];
    *reinterpret_cast<bf16x8*>(Bf + (size_t)idx * 8) = v;
}

// mel GEMM, K-split x4: r4 inner loop; block (tile,quarter) computes the partial
// over its K-quarter (4096 floats) for 32 rows, writes f32 partial.
// Quarter-major block order -> live B working set ~1MB per generation, L2-resident
// beside the nontemporal A stream (B HBM re-fetch was mel's gap-to-floor).
__global__ __launch_bounds__(256, 2) void gemm_mel_ks(
    const float* __restrict__ A0,
    const __bf16* __restrict__ Bf,
    float* __restrict__ part)
{
    const int tid = threadIdx.x;
    const int lane = tid & 63;
    const int wv = tid >> 6;
    const int quarter = blockIdx.x / 625;
    const int row_base = (blockIdx.x - quarter * 625) * 32;
    const int rif = lane & 15;
    const int kg = lane >> 4;
    const int s0 = quarter * 8;      // 8 steps of 512 floats per quarter

    __shared__ __align__(16) char ldsb[65536];

    f32x4 zero = {0.f, 0.f, 0.f, 0.f};
    f32x4 acc[2][8];
#pragma unroll
    for (int i = 0; i < 2; ++i)
#pragma unroll
        for (int j = 0; j < 8; ++j) acc[i][j] = zero;

    const bf16x8* __restrict__ BfV = reinterpret_cast<const bf16x8*>(Bf);

    f32x4 st[16];

    auto stage_load = [&](int s) {
#pragma unroll
        for (int j = 0; j < 16; ++j) {
            int seg = wv * 16 + j;
            int row = seg >> 1, halfseg = seg & 1;
            const float* gp = A0 + (size_t)(row_base + row) * 16384 + s * 512 + halfseg * 256 + (lane << 2);
            st[j] = __builtin_nontemporal_load(reinterpret_cast<const f32x4*>(gp));
        }
    };
    auto stage_write = [&](int buf) {
#pragma unroll
        for (int j = 0; j < 16; ++j) {
            int seg = wv * 16 + j;
            int row = seg >> 1, halfseg = seg & 1;
            int byte = row * 1024 + ((halfseg * 512 + lane * 8) ^ ((row & 7) << 4)) + buf * 32768;
            bf16x4 v;
            v[0] = (__bf16)st[j][0]; v[1] = (__bf16)st[j][1];
            v[2] = (__bf16)st[j][2]; v[3] = (__bf16)st[j][3];
            *reinterpret_cast<bf16x4*>(ldsb + byte) = v;
        }
    };
    auto compute2 = [&](int cur, int s, int kt0) {
#pragma unroll
        for (int kt = kt0; kt < kt0 + 2; ++kt) {
            bf16x8 af[2];
#pragma unroll
            for (int mi = 0; mi < 2; ++mi) {
                int row = mi * 16 + rif;
                int byte = row * 1024 + ((wv * 256 + kt * 64 + kg * 16) ^ ((rif & 7) << 4)) + cur * 32768;
                af[mi] = *reinterpret_cast<const bf16x8*>(ldsb + byte);
            }
            int ki = s * 16 + wv * 4 + kt;
            const bf16x8* bp = BfV + (size_t)ki * 512 + lane;
#pragma unroll
            for (int nf = 0; nf < 8; ++nf) {
                bf16x8 b = bp[nf * 64];
                acc[0][nf] = __builtin_amdgcn_mfma_f32_16x16x32_bf16(af[0], b, acc[0][nf], 0, 0, 0);
                acc[1][nf] = __builtin_amdgcn_mfma_f32_16x16x32_bf16(af[1], b, acc[1][nf], 0, 0, 0);
            }
        }
    };

    stage_load(s0);
    stage_write(0);
    for (int t = 0; t < 8; ++t) {
        int s = s0 + t;
        int cur = t & 1;
        if (t + 1 < 8) stage_load(s + 1);
        __syncthreads();
        compute2(cur, s, 0);
        compute2(cur, s, 2);
        if (t + 1 < 8) stage_write(cur ^ 1);
    }

    __syncthreads();
    float* red = reinterpret_cast<float*>(ldsb);
#pragma unroll
    for (int mi = 0; mi < 2; ++mi)
#pragma unroll
        for (int nf = 0; nf < 8; ++nf)
#pragma unroll
            for (int j = 0; j < 4; ++j)
                red[(wv * 32 + mi * 16 + kg * 4 + j) * HID + nf * 16 + rif] = acc[mi][nf][j];
    __syncthreads();
    float* pb = part + (size_t)quarter * 20000 * HID;
#pragma unroll
    for (int p = 0; p < 16; ++p) {
        int idx = tid + p * 256;
        int r = idx >> 7, c = idx & 127;
        float v = red[r * HID + c] + red[(32 + r) * HID + c]
                + red[(64 + r) * HID + c] + red[(96 + r) * HID + c];
        pb[(size_t)(row_base + r) * HID + c] = v;
    }
}

// m = relu(p0 + p1 + p2 + p3 + bias)
__global__ void combine_m(const float* __restrict__ part, const float* __restrict__ bias,
                          float* __restrict__ m) {
    int idx = blockIdx.x * 256 + threadIdx.x;   // 0..639999 f32x4 groups
    const size_t N = (size_t)20000 * HID / 4;
    const f32x4* p = reinterpret_cast<const f32x4*>(part);
    f32x4 b = *reinterpret_cast<const f32x4*>(bias + (idx & 31) * 4);
    f32x4 v = p[idx] + p[idx + N] + p[idx + 2 * N] + p[idx + 3 * N] + b;
    f32x4 r;
    r.x = fmaxf(v.x, 0.f); r.y = fmaxf(v.y, 0.f);
    r.z = fmaxf(v.z, 0.f); r.w = fmaxf(v.w, 0.f);
    reinterpret_cast<f32x4*>(m)[idx] = r;
}

// Fused: x = relu([text|m] @ Wcat + bcat) (LDS-only); h1 = x @ W1 -> bf16
__global__ __launch_bounds__(256) void gemm_cat_h1(
    const float* __restrict__ A0,
    const float* __restrict__ A1,
    const __bf16* __restrict__ Bf2,
    const __bf16* __restrict__ Bf3,
    const float* __restrict__ bcat,
    __bf16* __restrict__ h1)
{
    const int tid = threadIdx.x;
    const int lane = tid & 63;
    const int w = tid >> 6;
    const int row_base = blockIdx.x * 32;
    const int rif = lane & 15;
    const int kg = lane >> 4;

    f32x4 zero = {0.f, 0.f, 0.f, 0.f};
    f32x4 acc[2][8];
#pragma unroll
    for (int i = 0; i < 2; ++i)
#pragma unroll
        for (int j = 0; j < 8; ++j) acc[i][j] = zero;

    const bf16x8* __restrict__ Bf2V = reinterpret_cast<const bf16x8*>(Bf2);
    const int kstart = w * 224;

#pragma unroll
    for (int it = 0; it < 7; ++it) {
        const int k0 = kstart + it * 32;
        const int kc = k0 + kg * 8;
        bf16x8 af[2];
#pragma unroll
        for (int mi = 0; mi < 2; ++mi) {
            const int row = row_base + mi * 16 + rif;
            const float* ap;
            if (kc < 768) ap = A0 + (size_t)row * 768 + kc;
            else          ap = A1 + (size_t)row * HID + (kc - 768);
            const f32x4* apv = reinterpret_cast<const f32x4*>(ap);
            f32x4 v0 = apv[0];
            f32x4 v1 = apv[1];
            af[mi][0] = (__bf16)v0.x; af[mi][1] = (__bf16)v0.y;
            af[mi][2] = (__bf16)v0.z; af[mi][3] = (__bf16)v0.w;
            af[mi][4] = (__bf16)v1.x; af[mi][5] = (__bf16)v1.y;
            af[mi][6] = (__bf16)v1.z; af[mi][7] = (__bf16)v1.w;
        }
        const bf16x8* bp = Bf2V + (size_t)(k0 >> 5) * 512 + lane;
#pragma unroll
        for (int nf = 0; nf < 8; ++nf) {
            bf16x8 b = bp[nf * 64];
            acc[0][nf] = __builtin_amdgcn_mfma_f32_16x16x32_bf16(af[0], b, acc[0][nf], 0, 0, 0);
            acc[1][nf] = __builtin_amdgcn_mfma_f32_16x16x32_bf16(af[1], b, acc[1][nf], 0, 0, 0);
        }
    }

    __shared__ float red[4][32][HID];
    __shared__ __bf16 xs[32][136];

#pragma unroll
    for (int mi = 0; mi < 2; ++mi)
#pragma unroll
        for (int nf = 0; nf < 8; ++nf)
#pragma unroll
            for (int j = 0; j < 4; ++j)
                red[w][mi * 16 + kg * 4 + j][nf * 16 + rif] = acc[mi][nf][j];
    __syncthreads();
#pragma unroll
    for (int p = 0; p < 16; ++p) {
        int idx = tid + p * 256;
        int r = idx >> 7, c = idx & 127;
        float v = red[0][r][c] + red[1][r][c] + red[2][r][c] + red[3][r][c];
        v = fmaxf(v + bcat[c], 0.f);
        xs[r][c] = (__bf16)v;
    }
    __syncthreads();

    f32x4 acc2[2][8];
#pragma unroll
    for (int i = 0; i < 2; ++i)
#pragma unroll
        for (int j = 0; j < 8; ++j) acc2[i][j] = zero;

    {
        const int k0 = w * 32;
        bf16x8 af[2];
#pragma unroll
        for (int mi = 0; mi < 2; ++mi)
            af[mi] = *reinterpret_cast<const bf16x8*>(&xs[mi * 16 + rif][k0 + kg * 8]);
        const bf16x8* bp = reinterpret_cast<const bf16x8*>(Bf3) + (size_t)w * 512 + lane;
#pragma unroll
        for (int nf = 0; nf < 8; ++nf) {
            bf16x8 b = bp[nf * 64];
            acc2[0][nf] = __builtin_amdgcn_mfma_f32_16x16x32_bf16(af[0], b, acc2[0][nf], 0, 0, 0);
            acc2[1][nf] = __builtin_amdgcn_mfma_f32_16x16x32_bf16(af[1], b, acc2[1][nf], 0, 0, 0);
        }
    }

#pragma unroll
    for (int mi = 0; mi < 2; ++mi)
#pragma unroll
        for (int nf = 0; nf < 8; ++nf)
#pragma unroll
            for (int j = 0; j < 4; ++j)
                red[w][mi * 16 + kg * 4 + j][nf * 16 + rif] = acc2[mi][nf][j];
    __syncthreads();
#pragma unroll
    for (int p = 0; p < 16; ++p) {
        int idx = tid + p * 256;
        int r = idx >> 7, c = idx & 127;
        float v = red[0][r][c] + red[1][r][c] + red[2][r][c] + red[3][r][c];
        h1[(size_t)(row_base + r) * HID + c] = (__bf16)v;
    }
}

__global__ void count_dst(const int* __restrict__ dst, int* __restrict__ cnt, int E) {
    int e = blockIdx.x * 256 + threadIdx.x;
    if (e < E) atomicAdd(&cnt[dst[e]], 1);
}

__global__ __launch_bounds__(1024) void scan_block(const int* __restrict__ cnt,
    int* __restrict__ offs, float* __restrict__ dinv, int n) {
    int tid = threadIdx.x;
    int CH = (n + 1023) >> 10;
    int s0 = tid * CH;
    int s1 = min(s0 + CH, n);
    int sum = 0;
    for (int i = s0; i < s1; ++i) sum += cnt[i];
    int lane = tid & 63, wv = tid >> 6;
    int s = sum;
#pragma unroll
    for (int off = 1; off < 64; off <<= 1) {
        int t = __shfl_up(s, off);
        if (lane >= off) s += t;
    }
    __shared__ int wsum[16];
    __shared__ int wbase[16];
    if (lane == 63) wsum[wv] = s;
    __syncthreads();
    if (tid == 0) {
        int a = 0;
#pragma unroll
        for (int k = 0; k < 16; ++k) { wbase[k] = a; a += wsum[k]; }
    }
    __syncthreads();
    int run = wbase[wv] + (s - sum);
    for (int i = s0; i < s1; ++i) {
        int v = cnt[i];
        offs[i] = run;
        dinv[i] = rsqrtf((float)(v + 1));
        run += v;
    }
}

__global__ void fill_csr(const int* __restrict__ src, const int* __restrict__ dst,
                         const int* __restrict__ offs, int* __restrict__ fill,
                         int* __restrict__ srcs, int E) {
    int e = blockIdx.x * 256 + threadIdx.x;
    if (e >= E) return;
    int d = dst[e];
    int p = offs[d] + atomicAdd(&fill[d], 1);
    srcs[p] = src[e];
}

// Fused: yb = relu(dinv_i*(sum_s h[s]*dinv[s] + dinv_i*h[i]) + b1); h2 = yb @ W2
__global__ __launch_bounds__(128) void agg_h_w2(const __bf16* __restrict__ h,
    const float* __restrict__ dinv, const int* __restrict__ offs,
    const int* __restrict__ cnt, const int* __restrict__ srcs,
    const float* __restrict__ b1, const float* __restrict__ W2,
    float* __restrict__ h2, int n) {
    int i = blockIdx.x;
    int c = threadIdx.x;
    float di = dinv[i];
    float acc = (float)h[(size_t)i * HID + c] * di;
    int o = offs[i], e = cnt[i];
    int t = 0;
    for (; t + 4 <= e; t += 4) {
        int a0 = srcs[o + t], a1 = srcs[o + t + 1], a2 = srcs[o + t + 2], a3 = srcs[o + t + 3];
        float d0 = dinv[a0], d1 = dinv[a1], d2 = dinv[a2], d3 = dinv[a3];
        float v0 = (float)h[(size_t)a0 * HID + c], v1 = (float)h[(size_t)a1 * HID + c];
        float v2 = (float)h[(size_t)a2 * HID + c], v3 = (float)h[(size_t)a3 * HID + c];
        acc += v0 * d0 + v1 * d1 + v2 * d2 + v3 * d3;
    }
    for (; t < e; ++t) {
        int s = srcs[o + t];
        acc += (float)h[(size_t)s * HID + c] * dinv[s];
    }
    float yb = fmaxf(acc * di + b1[c], 0.f);
    float4 wr = *reinterpret_cast<const float4*>(W2 + c * 4);
    float p0 = yb * wr.x, p1 = yb * wr.y, p2 = yb * wr.z, p3 = yb * wr.w;
#pragma unroll
    for (int off = 32; off; off >>= 1) {
        p0 += __shfl_down(p0, off);
        p1 += __shfl_down(p1, off);
        p2 += __shfl_down(p2, off);
        p3 += __shfl_down(p3, off);
    }
    __shared__ float red[2][4];
    if ((c & 63) == 0) {
        int wv = c >> 6;
        red[wv][0] = p0; red[wv][1] = p1; red[wv][2] = p2; red[wv][3] = p3;
    }
    __syncthreads();
    if (c < 4) h2[(size_t)i * 4 + c] = red[0][c] + red[1][c];
}

__global__ void agg4(const float* __restrict__ h2, const float* __restrict__ dinv,
                     const int* __restrict__ offs, const int* __restrict__ cnt,
                     const int* __restrict__ srcs, const float* __restrict__ b2,
                     float* __restrict__ out, int n) {
    int gid = blockIdx.x * 256 + threadIdx.x;
    int i = gid >> 2;
    int c = gid & 3;
    if (i >= n) return;
    float di = dinv[i];
    float acc = h2[(size_t)i * 4 + c] * di;
    int o = offs[i], e = cnt[i];
    int t = 0;
    for (; t + 4 <= e; t += 4) {
        int a0 = srcs[o + t], a1 = srcs[o + t + 1], a2 = srcs[o + t + 2], a3 = srcs[o + t + 3];
        float v0 = h2[(size_t)a0 * 4 + c] * dinv[a0];
        float v1 = h2[(size_t)a1 * 4 + c] * dinv[a1];
        float v2 = h2[(size_t)a2 * 4 + c] * dinv[a2];
        float v3 = h2[(size_t)a3 * 4 + c] * dinv[a3];
        acc += v0 + v1 + v2 + v3;
    }
    for (; t < e; ++t) {
        int s = srcs[o + t];
        acc += h2[(size_t)s * 4 + c] * dinv[s];
    }
    out[(size_t)i * 4 + c] = acc * di + b2[c];
}

extern "C" void kernel_launch(void* const* d_in, const int* in_sizes, int n_in,
                              void* d_out, int out_size, void* d_ws, size_t ws_size,
                              hipStream_t stream) {
    const float* text = (const float*)d_in[0];
    const float* mel  = (const float*)d_in[1];
    const int*   ei   = (const int*)d_in[2];
    const float* Wmel = (const float*)d_in[3];
    const float* bmel = (const float*)d_in[4];
    const float* Wcat = (const float*)d_in[5];
    const float* bcat = (const float*)d_in[6];
    const float* W1   = (const float*)d_in[7];
    const float* b1   = (const float*)d_in[8];
    const float* W2   = (const float*)d_in[9];
    const float* b2   = (const float*)d_in[10];
    float* out = (float*)d_out;

    const int n = in_sizes[0] / 768;   // 20000
    const int E = in_sizes[2] / 2;     // 640000
    const int Kmel = 16384;
    const int Kcat = 896;

    char* ws = (char*)d_ws;
    size_t off = 0;
    auto alloc = [&](size_t bytes) {
        void* p = ws + off;
        off += (bytes + 255) & ~(size_t)255;
        return p;
    };
    __bf16* Bf1 = (__bf16*)alloc((size_t)Kmel * HID * 2);
    __bf16* Bf2 = (__bf16*)alloc((size_t)Kcat * HID * 2);
    __bf16* Bf3 = (__bf16*)alloc((size_t)HID * HID * 2);
    float* part = (float*)alloc((size_t)4 * n * HID * 4);
    float* m    = (float*)alloc((size_t)n * HID * 4);
    __bf16* h1  = (__bf16*)alloc((size_t)n * HID * 2);
    float* h2   = (float*)alloc((size_t)n * 4 * 4);
    int* cnt    = (int*)alloc((size_t)n * 4);
    int* offs   = (int*)alloc((size_t)n * 4);
    int* fill   = (int*)alloc((size_t)n * 4);
    float* dinv = (float*)alloc((size_t)n * 4);
    int* srcs   = (int*)alloc((size_t)E * 4);
    (void)ws_size; (void)n_in; (void)out_size;

    const int* srcI = ei;
    const int* dstI = ei + E;

    // ---- degrees + CSR ----
    (void)hipMemsetAsync(cnt, 0, n * 4, stream);
    (void)hipMemsetAsync(fill, 0, n * 4, stream);
    count_dst<<<(E + 255) / 256, 256, 0, stream>>>(dstI, cnt, E);
    scan_block<<<1, 1024, 0, stream>>>(cnt, offs, dinv, n);
    fill_csr<<<(E + 255) / 256, 256, 0, stream>>>(srcI, dstI, offs, fill, srcs, E);

    // ---- pack weights ----
    pack_b_frag<<<(Kmel / 32 * 512 + 255) / 256, 256, 0, stream>>>(Wmel, Bf1, Kmel / 32);
    pack_b_frag<<<(Kcat / 32 * 512 + 255) / 256, 256, 0, stream>>>(Wcat, Bf2, Kcat / 32);
    pack_b_frag<<<(HID / 32 * 512 + 255) / 256, 256, 0, stream>>>(W1, Bf3, HID / 32);

    // mel GEMM: K-split x4, 2500 quarter-K blocks (live B working set ~1MB)
    gemm_mel_ks<<<2500, 256, 0, stream>>>(mel, Bf1, part);
    // m = relu(p0+p1+p2+p3+bmel)
    combine_m<<<(n * HID / 4) / 256, 256, 0, stream>>>(part, bmel, m);
    // x = relu([text|m] @ Wcat + bcat); h1 = x @ W1 -> bf16   (fused)
    gemm_cat_h1<<<n / 32, 256, 0, stream>>>(text, m, Bf2, Bf3, bcat, h1);
    // h2 = relu(agg(h1)+b1) @ W2    (fused)
    agg_h_w2<<<n, 128, 0, stream>>>(h1, dinv, offs, cnt, srcs, b1, W2, h2, n);
    // out = agg(h2) + b2
    agg4<<<(n * 4 + 255) / 256, 256, 0, stream>>>(h2, dinv, offs, cnt, srcs, b2, out, n);
}

// Round 12
// 455.047 us; speedup vs baseline: 1.8637x; 1.0250x over previous
//
#include <hip/hip_runtime.h>
#include <hip/hip_bf16.h>
#include <cstdint>

typedef float f32x4 __attribute__((ext_vector_type(4)));
typedef __bf16 bf16x8 __attribute__((ext_vector_type(8)));
typedef __bf16 bf16x4 __attribute__((ext_vector_type(4)));
typedef __bf16 bf16x2 __attribute__((ext_vector_type(2)));

#define HID 128

// Merged pack: W [K][128] fp32 -> fragment-major bf16 for Wmel, Wcat, W1.
__global__ void pack_all(const float* __restrict__ Wa, const float* __restrict__ Wb,
                         const float* __restrict__ Wc,
                         __bf16* __restrict__ Ba, __bf16* __restrict__ Bb,
                         __bf16* __restrict__ Bc) {
    int idx = blockIdx.x * 256 + threadIdx.x;
    const int T1 = 512 * 512;   // Kmel/32 * 512
    const int T2 = 28 * 512;    // Kcat/32 * 512
    const int T3 = 4 * 512;     // 128/32 * 512
    const float* W; __bf16* B; int li;
    if (idx < T1)            { W = Wa; B = Ba; li = idx; }
    else if (idx < T1 + T2)  { W = Wb; B = Bb; li = idx - T1; }
    else if (idx < T1 + T2 + T3) { W = Wc; B = Bc; li = idx - T1 - T2; }
    else return;
    int lane = li & 63;
    int nf = (li >> 6) & 7;
    int ki = li >> 9;
    int n = nf * 16 + (lane & 15);
    int kb = ki * 32 + ((lane >> 4) * 8);
    bf16x8 v;
#pragma unroll
    for (int j = 0; j < 8; ++j) v[j] = (__bf16)W[(size_t)(kb + j) * HID + n];
    *reinterpret_cast<bf16x8*>(B + (size_t)li * 8) = v;
}

// mel GEMM, K-split x4 (r11 config, unchanged).
__global__ __launch_bounds__(256, 2) void gemm_mel_ks(
    const float* __restrict__ A0,
    const __bf16* __restrict__ Bf,
    float* __restrict__ part)
{
    const int tid = threadIdx.x;
    const int lane = tid & 63;
    const int wv = tid >> 6;
    const int quarter = blockIdx.x / 625;
    const int row_base = (blockIdx.x - quarter * 625) * 32;
    const int rif = lane & 15;
    const int kg = lane >> 4;
    const int s0 = quarter * 8;

    __shared__ __align__(16) char ldsb[65536];

    f32x4 zero = {0.f, 0.f, 0.f, 0.f};
    f32x4 acc[2][8];
#pragma unroll
    for (int i = 0; i < 2; ++i)
#pragma unroll
        for (int j = 0; j < 8; ++j) acc[i][j] = zero;

    const bf16x8* __restrict__ BfV = reinterpret_cast<const bf16x8*>(Bf);

    f32x4 st[16];

    auto stage_load = [&](int s) {
#pragma unroll
        for (int j = 0; j < 16; ++j) {
            int seg = wv * 16 + j;
            int row = seg >> 1, halfseg = seg & 1;
            const float* gp = A0 + (size_t)(row_base + row) * 16384 + s * 512 + halfseg * 256 + (lane << 2);
            st[j] = __builtin_nontemporal_load(reinterpret_cast<const f32x4*>(gp));
        }
    };
    auto stage_write = [&](int buf) {
#pragma unroll
        for (int j = 0; j < 16; ++j) {
            int seg = wv * 16 + j;
            int row = seg >> 1, halfseg = seg & 1;
            int byte = row * 1024 + ((halfseg * 512 + lane * 8) ^ ((row & 7) << 4)) + buf * 32768;
            bf16x4 v;
            v[0] = (__bf16)st[j][0]; v[1] = (__bf16)st[j][1];
            v[2] = (__bf16)st[j][2]; v[3] = (__bf16)st[j][3];
            *reinterpret_cast<bf16x4*>(ldsb + byte) = v;
        }
    };
    auto compute2 = [&](int cur, int s, int kt0) {
#pragma unroll
        for (int kt = kt0; kt < kt0 + 2; ++kt) {
            bf16x8 af[2];
#pragma unroll
            for (int mi = 0; mi < 2; ++mi) {
                int row = mi * 16 + rif;
                int byte = row * 1024 + ((wv * 256 + kt * 64 + kg * 16) ^ ((rif & 7) << 4)) + cur * 32768;
                af[mi] = *reinterpret_cast<const bf16x8*>(ldsb + byte);
            }
            int ki = s * 16 + wv * 4 + kt;
            const bf16x8* bp = BfV + (size_t)ki * 512 + lane;
#pragma unroll
            for (int nf = 0; nf < 8; ++nf) {
                bf16x8 b = bp[nf * 64];
                acc[0][nf] = __builtin_amdgcn_mfma_f32_16x16x32_bf16(af[0], b, acc[0][nf], 0, 0, 0);
                acc[1][nf] = __builtin_amdgcn_mfma_f32_16x16x32_bf16(af[1], b, acc[1][nf], 0, 0, 0);
            }
        }
    };

    stage_load(s0);
    stage_write(0);
    for (int t = 0; t < 8; ++t) {
        int s = s0 + t;
        int cur = t & 1;
        if (t + 1 < 8) stage_load(s + 1);
        __syncthreads();
        compute2(cur, s, 0);
        compute2(cur, s, 2);
        if (t + 1 < 8) stage_write(cur ^ 1);
    }

    __syncthreads();
    float* red = reinterpret_cast<float*>(ldsb);
#pragma unroll
    for (int mi = 0; mi < 2; ++mi)
#pragma unroll
        for (int nf = 0; nf < 8; ++nf)
#pragma unroll
            for (int j = 0; j < 4; ++j)
                red[(wv * 32 + mi * 16 + kg * 4 + j) * HID + nf * 16 + rif] = acc[mi][nf][j];
    __syncthreads();
    float* pb = part + (size_t)quarter * 20000 * HID;
#pragma unroll
    for (int p = 0; p < 16; ++p) {
        int idx = tid + p * 256;
        int r = idx >> 7, c = idx & 127;
        float v = red[r * HID + c] + red[(32 + r) * HID + c]
                + red[(64 + r) * HID + c] + red[(96 + r) * HID + c];
        pb[(size_t)(row_base + r) * HID + c] = v;
    }
}

// m = (bf16)relu(p0+p1+p2+p3+bias) — identical values to cat's former in-reg cvt.
__global__ void combine_m(const float* __restrict__ part, const float* __restrict__ bias,
                          __bf16* __restrict__ m) {
    int idx = blockIdx.x * 256 + threadIdx.x;
    const size_t N = (size_t)20000 * HID / 4;
    const f32x4* p = reinterpret_cast<const f32x4*>(part);
    f32x4 b = *reinterpret_cast<const f32x4*>(bias + (idx & 31) * 4);
    f32x4 v = p[idx] + p[idx + N] + p[idx + 2 * N] + p[idx + 3 * N] + b;
    bf16x4 r;
    r[0] = (__bf16)fmaxf(v.x, 0.f); r[1] = (__bf16)fmaxf(v.y, 0.f);
    r[2] = (__bf16)fmaxf(v.z, 0.f); r[3] = (__bf16)fmaxf(v.w, 0.f);
    *reinterpret_cast<bf16x4*>(m + (size_t)idx * 4) = r;
}

// Fused: x = relu([text|m] @ Wcat + bcat) (LDS-only); h1s = (x @ W1)*dinv -> bf16
__global__ __launch_bounds__(256) void gemm_cat_h1(
    const float* __restrict__ A0,     // text [n][768] f32
    const __bf16* __restrict__ A1,    // m [n][128] bf16
    const __bf16* __restrict__ Bf2,
    const __bf16* __restrict__ Bf3,
    const float* __restrict__ bcat,
    const float* __restrict__ dinv,
    __bf16* __restrict__ h1)
{
    const int tid = threadIdx.x;
    const int lane = tid & 63;
    const int w = tid >> 6;
    const int row_base = blockIdx.x * 32;
    const int rif = lane & 15;
    const int kg = lane >> 4;

    f32x4 zero = {0.f, 0.f, 0.f, 0.f};
    f32x4 acc[2][8];
#pragma unroll
    for (int i = 0; i < 2; ++i)
#pragma unroll
        for (int j = 0; j < 8; ++j) acc[i][j] = zero;

    const bf16x8* __restrict__ Bf2V = reinterpret_cast<const bf16x8*>(Bf2);
    const int kstart = w * 224;

#pragma unroll
    for (int it = 0; it < 7; ++it) {
        const int k0 = kstart + it * 32;
        const int kc = k0 + kg * 8;
        bf16x8 af[2];
#pragma unroll
        for (int mi = 0; mi < 2; ++mi) {
            const int row = row_base + mi * 16 + rif;
            if (k0 < 768) {   // uniform per iteration (k0 multiple of 32)
                const f32x4* apv = reinterpret_cast<const f32x4*>(A0 + (size_t)row * 768 + kc);
                f32x4 v0 = __builtin_nontemporal_load(apv);
                f32x4 v1 = __builtin_nontemporal_load(apv + 1);
                af[mi][0] = (__bf16)v0.x; af[mi][1] = (__bf16)v0.y;
                af[mi][2] = (__bf16)v0.z; af[mi][3] = (__bf16)v0.w;
                af[mi][4] = (__bf16)v1.x; af[mi][5] = (__bf16)v1.y;
                af[mi][6] = (__bf16)v1.z; af[mi][7] = (__bf16)v1.w;
            } else {
                af[mi] = *reinterpret_cast<const bf16x8*>(A1 + (size_t)row * HID + (kc - 768));
            }
        }
        const bf16x8* bp = Bf2V + (size_t)(k0 >> 5) * 512 + lane;
#pragma unroll
        for (int nf = 0; nf < 8; ++nf) {
            bf16x8 b = bp[nf * 64];
            acc[0][nf] = __builtin_amdgcn_mfma_f32_16x16x32_bf16(af[0], b, acc[0][nf], 0, 0, 0);
            acc[1][nf] = __builtin_amdgcn_mfma_f32_16x16x32_bf16(af[1], b, acc[1][nf], 0, 0, 0);
        }
    }

    __shared__ float red[4][32][HID];
    __shared__ __bf16 xs[32][136];

#pragma unroll
    for (int mi = 0; mi < 2; ++mi)
#pragma unroll
        for (int nf = 0; nf < 8; ++nf)
#pragma unroll
            for (int j = 0; j < 4; ++j)
                red[w][mi * 16 + kg * 4 + j][nf * 16 + rif] = acc[mi][nf][j];
    __syncthreads();
#pragma unroll
    for (int p = 0; p < 16; ++p) {
        int idx = tid + p * 256;
        int r = idx >> 7, c = idx & 127;
        float v = red[0][r][c] + red[1][r][c] + red[2][r][c] + red[3][r][c];
        v = fmaxf(v + bcat[c], 0.f);
        xs[r][c] = (__bf16)v;
    }
    __syncthreads();

    f32x4 acc2[2][8];
#pragma unroll
    for (int i = 0; i < 2; ++i)
#pragma unroll
        for (int j = 0; j < 8; ++j) acc2[i][j] = zero;

    {
        const int k0 = w * 32;
        bf16x8 af[2];
#pragma unroll
        for (int mi = 0; mi < 2; ++mi)
            af[mi] = *reinterpret_cast<const bf16x8*>(&xs[mi * 16 + rif][k0 + kg * 8]);
        const bf16x8* bp = reinterpret_cast<const bf16x8*>(Bf3) + (size_t)w * 512 + lane;
#pragma unroll
        for (int nf = 0; nf < 8; ++nf) {
            bf16x8 b = bp[nf * 64];
            acc2[0][nf] = __builtin_amdgcn_mfma_f32_16x16x32_bf16(af[0], b, acc2[0][nf], 0, 0, 0);
            acc2[1][nf] = __builtin_amdgcn_mfma_f32_16x16x32_bf16(af[1], b, acc2[1][nf], 0, 0, 0);
        }
    }

#pragma unroll
    for (int mi = 0; mi < 2; ++mi)
#pragma unroll
        for (int nf = 0; nf < 8; ++nf)
#pragma unroll
            for (int j = 0; j < 4; ++j)
                red[w][mi * 16 + kg * 4 + j][nf * 16 + rif] = acc2[mi][nf][j];
    __syncthreads();
#pragma unroll
    for (int p = 0; p < 16; ++p) {
        int idx = tid + p * 256;
        int r = idx >> 7, c = idx & 127;
        float v = red[0][r][c] + red[1][r][c] + red[2][r][c] + red[3][r][c];
        // store pre-scaled: h1s = h1 * dinv[row]  (agg no longer gathers dinv)
        h1[(size_t)(row_base + r) * HID + c] = (__bf16)(v * dinv[row_base + r]);
    }
}

__global__ void count_dst(const int* __restrict__ dst, int* __restrict__ cnt, int E) {
    int e = blockIdx.x * 256 + threadIdx.x;
    if (e < E) atomicAdd(&cnt[dst[e]], 1);
}

__global__ __launch_bounds__(1024) void scan_block(const int* __restrict__ cnt,
    int* __restrict__ offs, float* __restrict__ dinv, int n) {
    int tid = threadIdx.x;
    int CH = (n + 1023) >> 10;
    int s0 = tid * CH;
    int s1 = min(s0 + CH, n);
    int sum = 0;
    for (int i = s0; i < s1; ++i) sum += cnt[i];
    int lane = tid & 63, wv = tid >> 6;
    int s = sum;
#pragma unroll
    for (int off = 1; off < 64; off <<= 1) {
        int t = __shfl_up(s, off);
        if (lane >= off) s += t;
    }
    __shared__ int wsum[16];
    __shared__ int wbase[16];
    if (lane == 63) wsum[wv] = s;
    __syncthreads();
    if (tid == 0) {
        int a = 0;
#pragma unroll
        for (int k = 0; k < 16; ++k) { wbase[k] = a; a += wsum[k]; }
    }
    __syncthreads();
    int run = wbase[wv] + (s - sum);
    for (int i = s0; i < s1; ++i) {
        int v = cnt[i];
        offs[i] = run;
        dinv[i] = rsqrtf((float)(v + 1));
        run += v;
    }
}

__global__ void fill_csr(const int* __restrict__ src, const int* __restrict__ dst,
                         const int* __restrict__ offs, int* __restrict__ fill,
                         int* __restrict__ srcs, int E) {
    int e = blockIdx.x * 256 + threadIdx.x;
    if (e >= E) return;
    int d = dst[e];
    int p = offs[d] + atomicAdd(&fill[d], 1);
    srcs[p] = src[e];
}

// h1s is pre-scaled (h1*dinv). yb = relu((h1s[i] + sum_s h1s[s])*di + b1);
// h2s = (yb @ W2) * di. 64 threads/block: thread c owns cols {2c, 2c+1}.
__global__ __launch_bounds__(64) void agg_h_w2(const __bf16* __restrict__ hs,
    const float* __restrict__ dinv, const int* __restrict__ offs,
    const int* __restrict__ cnt, const int* __restrict__ srcs,
    const float* __restrict__ b1, const float* __restrict__ W2,
    float* __restrict__ h2, int n) {
    int i = blockIdx.x;
    int c = threadIdx.x;
    float di = dinv[i];
    const int col = 2 * c;
    bf16x2 hv = *reinterpret_cast<const bf16x2*>(hs + (size_t)i * HID + col);
    float a0 = (float)hv[0];
    float a1 = (float)hv[1];
    int o = offs[i], e = cnt[i];
    int t = 0;
    for (; t + 4 <= e; t += 4) {
        int s0 = srcs[o + t], s1 = srcs[o + t + 1], s2 = srcs[o + t + 2], s3 = srcs[o + t + 3];
        bf16x2 v0 = *reinterpret_cast<const bf16x2*>(hs + (size_t)s0 * HID + col);
        bf16x2 v1 = *reinterpret_cast<const bf16x2*>(hs + (size_t)s1 * HID + col);
        bf16x2 v2 = *reinterpret_cast<const bf16x2*>(hs + (size_t)s2 * HID + col);
        bf16x2 v3 = *reinterpret_cast<const bf16x2*>(hs + (size_t)s3 * HID + col);
        a0 += (float)v0[0] + (float)v1[0] + (float)v2[0] + (float)v3[0];
        a1 += (float)v0[1] + (float)v1[1] + (float)v2[1] + (float)v3[1];
    }
    for (; t < e; ++t) {
        int s = srcs[o + t];
        bf16x2 v = *reinterpret_cast<const bf16x2*>(hs + (size_t)s * HID + col);
        a0 += (float)v[0];
        a1 += (float)v[1];
    }
    float yb0 = fmaxf(a0 * di + b1[col], 0.f);
    float yb1 = fmaxf(a1 * di + b1[col + 1], 0.f);
    float4 w0 = *reinterpret_cast<const float4*>(W2 + col * 4);
    float4 w1 = *reinterpret_cast<const float4*>(W2 + col * 4 + 4);
    float p0 = yb0 * w0.x + yb1 * w1.x;
    float p1 = yb0 * w0.y + yb1 * w1.y;
    float p2 = yb0 * w0.z + yb1 * w1.z;
    float p3 = yb0 * w0.w + yb1 * w1.w;
#pragma unroll
    for (int off = 32; off; off >>= 1) {
        p0 += __shfl_down(p0, off);
        p1 += __shfl_down(p1, off);
        p2 += __shfl_down(p2, off);
        p3 += __shfl_down(p3, off);
    }
    if (c == 0) {
        // store pre-scaled h2s = h2 * di
        float4 r = {p0 * di, p1 * di, p2 * di, p3 * di};
        *reinterpret_cast<float4*>(h2 + (size_t)i * 4) = r;
    }
}

// out = (h2s[i] + sum_s h2s[s]) * di + b2   (h2s pre-scaled)
__global__ void agg4(const float* __restrict__ h2s, const float* __restrict__ dinv,
                     const int* __restrict__ offs, const int* __restrict__ cnt,
                     const int* __restrict__ srcs, const float* __restrict__ b2,
                     float* __restrict__ out, int n) {
    int gid = blockIdx.x * 256 + threadIdx.x;
    int i = gid >> 2;
    int c = gid & 3;
    if (i >= n) return;
    float di = dinv[i];
    float acc = h2s[(size_t)i * 4 + c];
    int o = offs[i], e = cnt[i];
    int t = 0;
    for (; t + 4 <= e; t += 4) {
        int a0 = srcs[o + t], a1 = srcs[o + t + 1], a2 = srcs[o + t + 2], a3 = srcs[o + t + 3];
        acc += h2s[(size_t)a0 * 4 + c] + h2s[(size_t)a1 * 4 + c]
             + h2s[(size_t)a2 * 4 + c] + h2s[(size_t)a3 * 4 + c];
    }
    for (; t < e; ++t) {
        int s = srcs[o + t];
        acc += h2s[(size_t)s * 4 + c];
    }
    out[(size_t)i * 4 + c] = acc * di + b2[c];
}

extern "C" void kernel_launch(void* const* d_in, const int* in_sizes, int n_in,
                              void* d_out, int out_size, void* d_ws, size_t ws_size,
                              hipStream_t stream) {
    const float* text = (const float*)d_in[0];
    const float* mel  = (const float*)d_in[1];
    const int*   ei   = (const int*)d_in[2];
    const float* Wmel = (const float*)d_in[3];
    const float* bmel = (const float*)d_in[4];
    const float* Wcat = (const float*)d_in[5];
    const float* bcat = (const float*)d_in[6];
    const float* W1   = (const float*)d_in[7];
    const float* b1   = (const float*)d_in[8];
    const float* W2   = (const float*)d_in[9];
    const float* b2   = (const float*)d_in[10];
    float* out = (float*)d_out;

    const int n = in_sizes[0] / 768;   // 20000
    const int E = in_sizes[2] / 2;     // 640000
    const int Kmel = 16384;

    char* ws = (char*)d_ws;
    size_t off = 0;
    auto alloc = [&](size_t bytes) {
        void* p = ws + off;
        off += (bytes + 255) & ~(size_t)255;
        return p;
    };
    __bf16* Bf1 = (__bf16*)alloc((size_t)Kmel * HID * 2);
    __bf16* Bf2 = (__bf16*)alloc((size_t)896 * HID * 2);
    __bf16* Bf3 = (__bf16*)alloc((size_t)HID * HID * 2);
    float* part = (float*)alloc((size_t)4 * n * HID * 4);
    __bf16* m   = (__bf16*)alloc((size_t)n * HID * 2);
    __bf16* h1  = (__bf16*)alloc((size_t)n * HID * 2);
    float* h2   = (float*)alloc((size_t)n * 4 * 4);
    int* cnt    = (int*)alloc((size_t)n * 4);
    int* offs   = (int*)alloc((size_t)n * 4);
    int* fill   = (int*)alloc((size_t)n * 4);
    float* dinv = (float*)alloc((size_t)n * 4);
    int* srcs   = (int*)alloc((size_t)E * 4);
    (void)ws_size; (void)n_in; (void)out_size;

    const int* srcI = ei;
    const int* dstI = ei + E;

    // ---- degrees + CSR ----
    (void)hipMemsetAsync(cnt, 0, n * 4, stream);
    (void)hipMemsetAsync(fill, 0, n * 4, stream);
    count_dst<<<(E + 255) / 256, 256, 0, stream>>>(dstI, cnt, E);
    scan_block<<<1, 1024, 0, stream>>>(cnt, offs, dinv, n);
    fill_csr<<<(E + 255) / 256, 256, 0, stream>>>(srcI, dstI, offs, fill, srcs, E);

    // ---- pack all weights (one launch) ----
    pack_all<<<1088, 256, 0, stream>>>(Wmel, Wcat, W1, Bf1, Bf2, Bf3);

    // mel GEMM: K-split x4
    gemm_mel_ks<<<2500, 256, 0, stream>>>(mel, Bf1, part);
    // m(bf16) = relu(p0+p1+p2+p3+bmel)
    combine_m<<<(n * HID / 4) / 256, 256, 0, stream>>>(part, bmel, m);
    // x = relu([text|m] @ Wcat + bcat); h1s = (x @ W1)*dinv -> bf16
    gemm_cat_h1<<<n / 32, 256, 0, stream>>>(text, m, Bf2, Bf3, bcat, dinv, h1);
    // h2s = relu(agg(h1s)+b1) @ W2 * dinv
    agg_h_w2<<<n, 64, 0, stream>>>(h1, dinv, offs, cnt, srcs, b1, W2, h2, n);
    // out = agg(h2s) + b2
    agg4<<<(n * 4 + 255) / 256, 256, 0, stream>>>(h2, dinv, offs, cnt, srcs, b2, out, n);
}

// Round 13
// 435.413 us; speedup vs baseline: 1.9477x; 1.0451x over previous
//
#include <hip/hip_runtime.h>
#include <hip/hip_bf16.h>
#include <cstdint>

typedef float f32x4 __attribute__((ext_vector_type(4)));
typedef __bf16 bf16x8 __attribute__((ext_vector_type(8)));
typedef __bf16 bf16x4 __attribute__((ext_vector_type(4)));
typedef __bf16 bf16x2 __attribute__((ext_vector_type(2)));

#define HID 128

// Merged pack: W [K][128] fp32 -> fragment-major bf16 for Wmel, Wcat, W1.
__global__ void pack_all(const float* __restrict__ Wa, const float* __restrict__ Wb,
                         const float* __restrict__ Wc,
                         __bf16* __restrict__ Ba, __bf16* __restrict__ Bb,
                         __bf16* __restrict__ Bc) {
    int idx = blockIdx.x * 256 + threadIdx.x;
    const int T1 = 512 * 512;
    const int T2 = 28 * 512;
    const int T3 = 4 * 512;
    const float* W; __bf16* B; int li;
    if (idx < T1)            { W = Wa; B = Ba; li = idx; }
    else if (idx < T1 + T2)  { W = Wb; B = Bb; li = idx - T1; }
    else if (idx < T1 + T2 + T3) { W = Wc; B = Bc; li = idx - T1 - T2; }
    else return;
    int lane = li & 63;
    int nf = (li >> 6) & 7;
    int ki = li >> 9;
    int n = nf * 16 + (lane & 15);
    int kb = ki * 32 + ((lane >> 4) * 8);
    bf16x8 v;
#pragma unroll
    for (int j = 0; j < 8; ++j) v[j] = (__bf16)W[(size_t)(kb + j) * HID + n];
    *reinterpret_cast<bf16x8*>(B + (size_t)li * 8) = v;
}

// mel GEMM, K-split x4; partials now bf16 (half write traffic), nontemporal.
__global__ __launch_bounds__(256, 2) void gemm_mel_ks(
    const float* __restrict__ A0,
    const __bf16* __restrict__ Bf,
    __bf16* __restrict__ part)
{
    const int tid = threadIdx.x;
    const int lane = tid & 63;
    const int wv = tid >> 6;
    const int quarter = blockIdx.x / 625;
    const int row_base = (blockIdx.x - quarter * 625) * 32;
    const int rif = lane & 15;
    const int kg = lane >> 4;
    const int s0 = quarter * 8;

    __shared__ __align__(16) char ldsb[65536];

    f32x4 zero = {0.f, 0.f, 0.f, 0.f};
    f32x4 acc[2][8];
#pragma unroll
    for (int i = 0; i < 2; ++i)
#pragma unroll
        for (int j = 0; j < 8; ++j) acc[i][j] = zero;

    const bf16x8* __restrict__ BfV = reinterpret_cast<const bf16x8*>(Bf);

    f32x4 st[16];

    auto stage_load = [&](int s) {
#pragma unroll
        for (int j = 0; j < 16; ++j) {
            int seg = wv * 16 + j;
            int row = seg >> 1, halfseg = seg & 1;
            const float* gp = A0 + (size_t)(row_base + row) * 16384 + s * 512 + halfseg * 256 + (lane << 2);
            st[j] = __builtin_nontemporal_load(reinterpret_cast<const f32x4*>(gp));
        }
    };
    auto stage_write = [&](int buf) {
#pragma unroll
        for (int j = 0; j < 16; ++j) {
            int seg = wv * 16 + j;
            int row = seg >> 1, halfseg = seg & 1;
            int byte = row * 1024 + ((halfseg * 512 + lane * 8) ^ ((row & 7) << 4)) + buf * 32768;
            bf16x4 v;
            v[0] = (__bf16)st[j][0]; v[1] = (__bf16)st[j][1];
            v[2] = (__bf16)st[j][2]; v[3] = (__bf16)st[j][3];
            *reinterpret_cast<bf16x4*>(ldsb + byte) = v;
        }
    };
    auto compute2 = [&](int cur, int s, int kt0) {
#pragma unroll
        for (int kt = kt0; kt < kt0 + 2; ++kt) {
            bf16x8 af[2];
#pragma unroll
            for (int mi = 0; mi < 2; ++mi) {
                int row = mi * 16 + rif;
                int byte = row * 1024 + ((wv * 256 + kt * 64 + kg * 16) ^ ((rif & 7) << 4)) + cur * 32768;
                af[mi] = *reinterpret_cast<const bf16x8*>(ldsb + byte);
            }
            int ki = s * 16 + wv * 4 + kt;
            const bf16x8* bp = BfV + (size_t)ki * 512 + lane;
#pragma unroll
            for (int nf = 0; nf < 8; ++nf) {
                bf16x8 b = bp[nf * 64];
                acc[0][nf] = __builtin_amdgcn_mfma_f32_16x16x32_bf16(af[0], b, acc[0][nf], 0, 0, 0);
                acc[1][nf] = __builtin_amdgcn_mfma_f32_16x16x32_bf16(af[1], b, acc[1][nf], 0, 0, 0);
            }
        }
    };

    stage_load(s0);
    stage_write(0);
    for (int t = 0; t < 8; ++t) {
        int s = s0 + t;
        int cur = t & 1;
        if (t + 1 < 8) stage_load(s + 1);
        __syncthreads();
        compute2(cur, s, 0);
        compute2(cur, s, 2);
        if (t + 1 < 8) stage_write(cur ^ 1);
    }

    __syncthreads();
    float* red = reinterpret_cast<float*>(ldsb);
#pragma unroll
    for (int mi = 0; mi < 2; ++mi)
#pragma unroll
        for (int nf = 0; nf < 8; ++nf)
#pragma unroll
            for (int j = 0; j < 4; ++j)
                red[(wv * 32 + mi * 16 + kg * 4 + j) * HID + nf * 16 + rif] = acc[mi][nf][j];
    __syncthreads();
    __bf16* pb = part + (size_t)quarter * 20000 * HID;
#pragma unroll
    for (int p = 0; p < 8; ++p) {
        int idx = tid + p * 256;          // 0..2047
        int r = idx >> 6;                 // 0..31
        int c2 = (idx & 63) * 2;          // even col
        float v0 = red[r * HID + c2]     + red[(32 + r) * HID + c2]
                 + red[(64 + r) * HID + c2] + red[(96 + r) * HID + c2];
        float v1 = red[r * HID + c2 + 1] + red[(32 + r) * HID + c2 + 1]
                 + red[(64 + r) * HID + c2 + 1] + red[(96 + r) * HID + c2 + 1];
        union { bf16x2 h; unsigned int u; } cv;
        cv.h[0] = (__bf16)v0; cv.h[1] = (__bf16)v1;
        __builtin_nontemporal_store(cv.u,
            reinterpret_cast<unsigned int*>(pb + (size_t)(row_base + r) * HID + c2));
    }
}

// Fused: m = relu(sum partials + bmel) inline; x = relu([text|m]@Wcat + bcat);
// h1s = (x @ W1) * dinv -> bf16.
__global__ __launch_bounds__(256) void gemm_cat_h1(
    const float* __restrict__ A0,       // text [n][768] f32
    const __bf16* __restrict__ part,    // [4][n][128] bf16 partials
    const float* __restrict__ bmel,
    const __bf16* __restrict__ Bf2,
    const __bf16* __restrict__ Bf3,
    const float* __restrict__ bcat,
    const float* __restrict__ dinv,
    __bf16* __restrict__ h1)
{
    const int tid = threadIdx.x;
    const int lane = tid & 63;
    const int w = tid >> 6;
    const int row_base = blockIdx.x * 32;
    const int rif = lane & 15;
    const int kg = lane >> 4;

    f32x4 zero = {0.f, 0.f, 0.f, 0.f};
    f32x4 acc[2][8];
#pragma unroll
    for (int i = 0; i < 2; ++i)
#pragma unroll
        for (int j = 0; j < 8; ++j) acc[i][j] = zero;

    const bf16x8* __restrict__ Bf2V = reinterpret_cast<const bf16x8*>(Bf2);
    const int kstart = w * 224;
    const size_t N = (size_t)20000 * HID;

#pragma unroll
    for (int it = 0; it < 7; ++it) {
        const int k0 = kstart + it * 32;
        const int kc = k0 + kg * 8;
        bf16x8 af[2];
#pragma unroll
        for (int mi = 0; mi < 2; ++mi) {
            const int row = row_base + mi * 16 + rif;
            if (k0 < 768) {   // uniform per (w,it)
                const f32x4* apv = reinterpret_cast<const f32x4*>(A0 + (size_t)row * 768 + kc);
                f32x4 v0 = __builtin_nontemporal_load(apv);
                f32x4 v1 = __builtin_nontemporal_load(apv + 1);
                af[mi][0] = (__bf16)v0.x; af[mi][1] = (__bf16)v0.y;
                af[mi][2] = (__bf16)v0.z; af[mi][3] = (__bf16)v0.w;
                af[mi][4] = (__bf16)v1.x; af[mi][5] = (__bf16)v1.y;
                af[mi][6] = (__bf16)v1.z; af[mi][7] = (__bf16)v1.w;
            } else {
                const int mcol = kc - 768;
                const size_t base = (size_t)row * HID + mcol;
                bf16x8 q0 = *reinterpret_cast<const bf16x8*>(part + base);
                bf16x8 q1 = *reinterpret_cast<const bf16x8*>(part + N + base);
                bf16x8 q2 = *reinterpret_cast<const bf16x8*>(part + 2 * N + base);
                bf16x8 q3 = *reinterpret_cast<const bf16x8*>(part + 3 * N + base);
                const float* bp_ = bmel + mcol;
#pragma unroll
                for (int jj = 0; jj < 8; ++jj) {
                    float v = (float)q0[jj] + (float)q1[jj] + (float)q2[jj] + (float)q3[jj] + bp_[jj];
                    af[mi][jj] = (__bf16)fmaxf(v, 0.f);
                }
            }
        }
        const bf16x8* bp = Bf2V + (size_t)(k0 >> 5) * 512 + lane;
#pragma unroll
        for (int nf = 0; nf < 8; ++nf) {
            bf16x8 b = bp[nf * 64];
            acc[0][nf] = __builtin_amdgcn_mfma_f32_16x16x32_bf16(af[0], b, acc[0][nf], 0, 0, 0);
            acc[1][nf] = __builtin_amdgcn_mfma_f32_16x16x32_bf16(af[1], b, acc[1][nf], 0, 0, 0);
        }
    }

    __shared__ float red[4][32][HID];
    __shared__ __bf16 xs[32][136];

#pragma unroll
    for (int mi = 0; mi < 2; ++mi)
#pragma unroll
        for (int nf = 0; nf < 8; ++nf)
#pragma unroll
            for (int j = 0; j < 4; ++j)
                red[w][mi * 16 + kg * 4 + j][nf * 16 + rif] = acc[mi][nf][j];
    __syncthreads();
#pragma unroll
    for (int p = 0; p < 16; ++p) {
        int idx = tid + p * 256;
        int r = idx >> 7, c = idx & 127;
        float v = red[0][r][c] + red[1][r][c] + red[2][r][c] + red[3][r][c];
        v = fmaxf(v + bcat[c], 0.f);
        xs[r][c] = (__bf16)v;
    }
    __syncthreads();

    f32x4 acc2[2][8];
#pragma unroll
    for (int i = 0; i < 2; ++i)
#pragma unroll
        for (int j = 0; j < 8; ++j) acc2[i][j] = zero;

    {
        const int k0 = w * 32;
        bf16x8 af[2];
#pragma unroll
        for (int mi = 0; mi < 2; ++mi)
            af[mi] = *reinterpret_cast<const bf16x8*>(&xs[mi * 16 + rif][k0 + kg * 8]);
        const bf16x8* bp = reinterpret_cast<const bf16x8*>(Bf3) + (size_t)w * 512 + lane;
#pragma unroll
        for (int nf = 0; nf < 8; ++nf) {
            bf16x8 b = bp[nf * 64];
            acc2[0][nf] = __builtin_amdgcn_mfma_f32_16x16x32_bf16(af[0], b, acc2[0][nf], 0, 0, 0);
            acc2[1][nf] = __builtin_amdgcn_mfma_f32_16x16x32_bf16(af[1], b, acc2[1][nf], 0, 0, 0);
        }
    }

#pragma unroll
    for (int mi = 0; mi < 2; ++mi)
#pragma unroll
        for (int nf = 0; nf < 8; ++nf)
#pragma unroll
            for (int j = 0; j < 4; ++j)
                red[w][mi * 16 + kg * 4 + j][nf * 16 + rif] = acc2[mi][nf][j];
    __syncthreads();
#pragma unroll
    for (int p = 0; p < 16; ++p) {
        int idx = tid + p * 256;
        int r = idx >> 7, c = idx & 127;
        float v = red[0][r][c] + red[1][r][c] + red[2][r][c] + red[3][r][c];
        h1[(size_t)(row_base + r) * HID + c] = (__bf16)(v * dinv[row_base + r]);
    }
}

__global__ void count_dst(const int* __restrict__ dst, int* __restrict__ cnt, int E) {
    int e = blockIdx.x * 256 + threadIdx.x;
    if (e < E) atomicAdd(&cnt[dst[e]], 1);
}

// scan: offs[0..n-1] exclusive; offs[n] = E; dinv = rsqrt(deg+1)
__global__ __launch_bounds__(1024) void scan_block(const int* __restrict__ cnt,
    int* __restrict__ offs, float* __restrict__ dinv, int n) {
    int tid = threadIdx.x;
    int CH = (n + 1023) >> 10;
    int s0 = tid * CH;
    int s1 = min(s0 + CH, n);
    int sum = 0;
    for (int i = s0; i < s1; ++i) sum += cnt[i];
    int lane = tid & 63, wv = tid >> 6;
    int s = sum;
#pragma unroll
    for (int off = 1; off < 64; off <<= 1) {
        int t = __shfl_up(s, off);
        if (lane >= off) s += t;
    }
    __shared__ int wsum[16];
    __shared__ int wbase[16];
    if (lane == 63) wsum[wv] = s;
    __syncthreads();
    if (tid == 0) {
        int a = 0;
#pragma unroll
        for (int k = 0; k < 16; ++k) { wbase[k] = a; a += wsum[k]; }
        offs[n] = a;
    }
    __syncthreads();
    int run = wbase[wv] + (s - sum);
    for (int i = s0; i < s1; ++i) {
        int v = cnt[i];
        offs[i] = run;
        dinv[i] = rsqrtf((float)(v + 1));
        run += v;
    }
}

// fill: decrement cnt in place (no separate fill buffer)
__global__ void fill_csr(const int* __restrict__ src, const int* __restrict__ dst,
                         const int* __restrict__ offs, int* __restrict__ cnt,
                         int* __restrict__ srcs, int E) {
    int e = blockIdx.x * 256 + threadIdx.x;
    if (e >= E) return;
    int d = dst[e];
    int p = offs[d] + atomicAdd(&cnt[d], -1) - 1;
    srcs[p] = src[e];
}

// h1s pre-scaled. yb = relu((h1s[i]+sum_s h1s[s])*di + b1); h2s = (yb@W2)*di.
// 64 thr/block, 2 cols/thread, unroll x8.
__global__ __launch_bounds__(64) void agg_h_w2(const __bf16* __restrict__ hs,
    const float* __restrict__ dinv, const int* __restrict__ offs,
    const int* __restrict__ srcs,
    const float* __restrict__ b1, const float* __restrict__ W2,
    float* __restrict__ h2, int n) {
    int i = blockIdx.x;
    int c = threadIdx.x;
    float di = dinv[i];
    const int col = 2 * c;
    bf16x2 hv = *reinterpret_cast<const bf16x2*>(hs + (size_t)i * HID + col);
    float a0 = (float)hv[0];
    float a1 = (float)hv[1];
    int o = offs[i];
    int e = offs[i + 1] - o;
    int t = 0;
    for (; t + 8 <= e; t += 8) {
        int sx[8];
#pragma unroll
        for (int q = 0; q < 8; ++q) sx[q] = srcs[o + t + q];
        bf16x2 v[8];
#pragma unroll
        for (int q = 0; q < 8; ++q) v[q] = *reinterpret_cast<const bf16x2*>(hs + (size_t)sx[q] * HID + col);
#pragma unroll
        for (int q = 0; q < 8; ++q) { a0 += (float)v[q][0]; a1 += (float)v[q][1]; }
    }
    for (; t < e; ++t) {
        int s = srcs[o + t];
        bf16x2 v = *reinterpret_cast<const bf16x2*>(hs + (size_t)s * HID + col);
        a0 += (float)v[0];
        a1 += (float)v[1];
    }
    float yb0 = fmaxf(a0 * di + b1[col], 0.f);
    float yb1 = fmaxf(a1 * di + b1[col + 1], 0.f);
    float4 w0 = *reinterpret_cast<const float4*>(W2 + col * 4);
    float4 w1 = *reinterpret_cast<const float4*>(W2 + col * 4 + 4);
    float p0 = yb0 * w0.x + yb1 * w1.x;
    float p1 = yb0 * w0.y + yb1 * w1.y;
    float p2 = yb0 * w0.z + yb1 * w1.z;
    float p3 = yb0 * w0.w + yb1 * w1.w;
#pragma unroll
    for (int off = 32; off; off >>= 1) {
        p0 += __shfl_down(p0, off);
        p1 += __shfl_down(p1, off);
        p2 += __shfl_down(p2, off);
        p3 += __shfl_down(p3, off);
    }
    if (c == 0) {
        float4 r = {p0 * di, p1 * di, p2 * di, p3 * di};
        *reinterpret_cast<float4*>(h2 + (size_t)i * 4) = r;
    }
}

// out = (h2s[i] + sum_s h2s[s]) * di + b2
__global__ void agg4(const float* __restrict__ h2s, const float* __restrict__ dinv,
                     const int* __restrict__ offs,
                     const int* __restrict__ srcs, const float* __restrict__ b2,
                     float* __restrict__ out, int n) {
    int gid = blockIdx.x * 256 + threadIdx.x;
    int i = gid >> 2;
    int c = gid & 3;
    if (i >= n) return;
    float di = dinv[i];
    float acc = h2s[(size_t)i * 4 + c];
    int o = offs[i];
    int e = offs[i + 1] - o;
    int t = 0;
    for (; t + 4 <= e; t += 4) {
        int a0 = srcs[o + t], a1 = srcs[o + t + 1], a2 = srcs[o + t + 2], a3 = srcs[o + t + 3];
        acc += h2s[(size_t)a0 * 4 + c] + h2s[(size_t)a1 * 4 + c]
             + h2s[(size_t)a2 * 4 + c] + h2s[(size_t)a3 * 4 + c];
    }
    for (; t < e; ++t) {
        int s = srcs[o + t];
        acc += h2s[(size_t)s * 4 + c];
    }
    out[(size_t)i * 4 + c] = acc * di + b2[c];
}

extern "C" void kernel_launch(void* const* d_in, const int* in_sizes, int n_in,
                              void* d_out, int out_size, void* d_ws, size_t ws_size,
                              hipStream_t stream) {
    const float* text = (const float*)d_in[0];
    const float* mel  = (const float*)d_in[1];
    const int*   ei   = (const int*)d_in[2];
    const float* Wmel = (const float*)d_in[3];
    const float* bmel = (const float*)d_in[4];
    const float* Wcat = (const float*)d_in[5];
    const float* bcat = (const float*)d_in[6];
    const float* W1   = (const float*)d_in[7];
    const float* b1   = (const float*)d_in[8];
    const float* W2   = (const float*)d_in[9];
    const float* b2   = (const float*)d_in[10];
    float* out = (float*)d_out;

    const int n = in_sizes[0] / 768;   // 20000
    const int E = in_sizes[2] / 2;     // 640000
    const int Kmel = 16384;

    char* ws = (char*)d_ws;
    size_t off = 0;
    auto alloc = [&](size_t bytes) {
        void* p = ws + off;
        off += (bytes + 255) & ~(size_t)255;
        return p;
    };
    __bf16* Bf1 = (__bf16*)alloc((size_t)Kmel * HID * 2);
    __bf16* Bf2 = (__bf16*)alloc((size_t)896 * HID * 2);
    __bf16* Bf3 = (__bf16*)alloc((size_t)HID * HID * 2);
    __bf16* part = (__bf16*)alloc((size_t)4 * n * HID * 2);
    __bf16* h1  = (__bf16*)alloc((size_t)n * HID * 2);
    float* h2   = (float*)alloc((size_t)n * 4 * 4);
    int* cnt    = (int*)alloc((size_t)n * 4);
    int* offs   = (int*)alloc((size_t)(n + 1) * 4);
    float* dinv = (float*)alloc((size_t)n * 4);
    int* srcs   = (int*)alloc((size_t)E * 4);
    (void)ws_size; (void)n_in; (void)out_size;

    const int* srcI = ei;
    const int* dstI = ei + E;

    // ---- degrees + CSR (fill decrements cnt in place) ----
    (void)hipMemsetAsync(cnt, 0, n * 4, stream);
    count_dst<<<(E + 255) / 256, 256, 0, stream>>>(dstI, cnt, E);
    scan_block<<<1, 1024, 0, stream>>>(cnt, offs, dinv, n);
    fill_csr<<<(E + 255) / 256, 256, 0, stream>>>(srcI, dstI, offs, cnt, srcs, E);

    // ---- pack all weights (one launch) ----
    pack_all<<<1088, 256, 0, stream>>>(Wmel, Wcat, W1, Bf1, Bf2, Bf3);

    // mel GEMM: K-split x4, bf16 partials
    gemm_mel_ks<<<2500, 256, 0, stream>>>(mel, Bf1, part);
    // fused combine+cat: x = relu([text|relu(sum parts+bmel)]@Wcat+bcat); h1s=(x@W1)*dinv
    gemm_cat_h1<<<n / 32, 256, 0, stream>>>(text, part, bmel, Bf2, Bf3, bcat, dinv, h1);
    // h2s = relu(agg(h1s)+b1) @ W2 * dinv
    agg_h_w2<<<n, 64, 0, stream>>>(h1, dinv, offs, srcs, b1, W2, h2, n);
    // out = agg(h2s) + b2
    agg4<<<(n * 4 + 255) / 256, 256, 0, stream>>>(h2, dinv, offs, srcs, b2, out, n);
}

// Round 14
// 420.713 us; speedup vs baseline: 2.0158x; 1.0349x over previous
//
#include <hip/hip_runtime.h>
#include <hip/hip_bf16.h>
#include <cstdint>

typedef float f32x4 __attribute__((ext_vector_type(4)));
typedef __bf16 bf16x8 __attribute__((ext_vector_type(8)));
typedef __bf16 bf16x4 __attribute__((ext_vector_type(4)));
typedef __bf16 bf16x2 __attribute__((ext_vector_type(2)));

#define HID 128

// Fused: blocks 0..255 count dst-degrees (grid-stride); blocks 256..1343 pack
// Wmel/Wcat/W1 fp32 -> fragment-major bf16. Independent work, one launch.
__global__ void count_pack(const int* __restrict__ dstI, int* __restrict__ cnt, int E,
                           const float* __restrict__ Wa, const float* __restrict__ Wb,
                           const float* __restrict__ Wc,
                           __bf16* __restrict__ Ba, __bf16* __restrict__ Bb,
                           __bf16* __restrict__ Bc) {
    if (blockIdx.x < 256) {
        for (int e = blockIdx.x * 256 + threadIdx.x; e < E; e += 65536)
            atomicAdd(&cnt[dstI[e]], 1);
        return;
    }
    int idx = (blockIdx.x - 256) * 256 + threadIdx.x;   // 0..278527 exactly
    const int T1 = 512 * 512;
    const int T2 = 28 * 512;
    const float* W; __bf16* B; int li;
    if (idx < T1)            { W = Wa; B = Ba; li = idx; }
    else if (idx < T1 + T2)  { W = Wb; B = Bb; li = idx - T1; }
    else                     { W = Wc; B = Bc; li = idx - T1 - T2; }
    int lane = li & 63;
    int nf = (li >> 6) & 7;
    int ki = li >> 9;
    int n = nf * 16 + (lane & 15);
    int kb = ki * 32 + ((lane >> 4) * 8);
    bf16x8 v;
#pragma unroll
    for (int j = 0; j < 8; ++j) v[j] = (__bf16)W[(size_t)(kb + j) * HID + n];
    *reinterpret_cast<bf16x8*>(B + (size_t)li * 8) = v;
}

// mel GEMM (K-split x4, bf16 partials) with CSR-fill blocks interleaved:
// every 11th block (b%11==10, 250 total) does a short grid-stride fill pass
// (10 edges/thread, ~3us) then exits, returning its slot to mel. Fill's
// atomics+scatter hide inside mel's HBM-bound 280us instead of running serial.
__global__ __launch_bounds__(256, 2) void gemm_mel_fill(
    const float* __restrict__ A0,
    const __bf16* __restrict__ Bf,
    __bf16* __restrict__ part,
    const int* __restrict__ srcI, const int* __restrict__ dstI,
    const int* __restrict__ offs, int* __restrict__ cnt,
    int* __restrict__ srcs, int E)
{
    const int b = blockIdx.x;
    if ((b % 11) == 10) {
        // ---- fill path (block-uniform branch; no barriers used) ----
        int fid = b / 11;                       // 0..249
        for (int e = fid * 256 + threadIdx.x; e < E; e += 64000) {
            int d = dstI[e];
            int p = offs[d] + atomicAdd(&cnt[d], -1) - 1;
            srcs[p] = srcI[e];
        }
        return;
    }
    const int bid = b - b / 11;                 // 0..2499 (mel tile index)
    const int tid = threadIdx.x;
    const int lane = tid & 63;
    const int wv = tid >> 6;
    const int quarter = bid / 625;
    const int row_base = (bid - quarter * 625) * 32;
    const int rif = lane & 15;
    const int kg = lane >> 4;
    const int s0 = quarter * 8;

    __shared__ __align__(16) char ldsb[65536];

    f32x4 zero = {0.f, 0.f, 0.f, 0.f};
    f32x4 acc[2][8];
#pragma unroll
    for (int i = 0; i < 2; ++i)
#pragma unroll
        for (int j = 0; j < 8; ++j) acc[i][j] = zero;

    const bf16x8* __restrict__ BfV = reinterpret_cast<const bf16x8*>(Bf);

    f32x4 st[16];

    auto stage_load = [&](int s) {
#pragma unroll
        for (int j = 0; j < 16; ++j) {
            int seg = wv * 16 + j;
            int row = seg >> 1, halfseg = seg & 1;
            const float* gp = A0 + (size_t)(row_base + row) * 16384 + s * 512 + halfseg * 256 + (lane << 2);
            st[j] = __builtin_nontemporal_load(reinterpret_cast<const f32x4*>(gp));
        }
    };
    auto stage_write = [&](int buf) {
#pragma unroll
        for (int j = 0; j < 16; ++j) {
            int seg = wv * 16 + j;
            int row = seg >> 1, halfseg = seg & 1;
            int byte = row * 1024 + ((halfseg * 512 + lane * 8) ^ ((row & 7) << 4)) + buf * 32768;
            bf16x4 v;
            v[0] = (__bf16)st[j][0]; v[1] = (__bf16)st[j][1];
            v[2] = (__bf16)st[j][2]; v[3] = (__bf16)st[j][3];
            *reinterpret_cast<bf16x4*>(ldsb + byte) = v;
        }
    };
    auto compute2 = [&](int cur, int s, int kt0) {
#pragma unroll
        for (int kt = kt0; kt < kt0 + 2; ++kt) {
            bf16x8 af[2];
#pragma unroll
            for (int mi = 0; mi < 2; ++mi) {
                int row = mi * 16 + rif;
                int byte = row * 1024 + ((wv * 256 + kt * 64 + kg * 16) ^ ((rif & 7) << 4)) + cur * 32768;
                af[mi] = *reinterpret_cast<const bf16x8*>(ldsb + byte);
            }
            int ki = s * 16 + wv * 4 + kt;
            const bf16x8* bp = BfV + (size_t)ki * 512 + lane;
#pragma unroll
            for (int nf = 0; nf < 8; ++nf) {
                bf16x8 bq = bp[nf * 64];
                acc[0][nf] = __builtin_amdgcn_mfma_f32_16x16x32_bf16(af[0], bq, acc[0][nf], 0, 0, 0);
                acc[1][nf] = __builtin_amdgcn_mfma_f32_16x16x32_bf16(af[1], bq, acc[1][nf], 0, 0, 0);
            }
        }
    };

    stage_load(s0);
    stage_write(0);
    for (int t = 0; t < 8; ++t) {
        int s = s0 + t;
        int cur = t & 1;
        if (t + 1 < 8) stage_load(s + 1);
        __syncthreads();
        compute2(cur, s, 0);
        compute2(cur, s, 2);
        if (t + 1 < 8) stage_write(cur ^ 1);
    }

    __syncthreads();
    float* red = reinterpret_cast<float*>(ldsb);
#pragma unroll
    for (int mi = 0; mi < 2; ++mi)
#pragma unroll
        for (int nf = 0; nf < 8; ++nf)
#pragma unroll
            for (int j = 0; j < 4; ++j)
                red[(wv * 32 + mi * 16 + kg * 4 + j) * HID + nf * 16 + rif] = acc[mi][nf][j];
    __syncthreads();
    __bf16* pb = part + (size_t)quarter * 20000 * HID;
#pragma unroll
    for (int p = 0; p < 8; ++p) {
        int idx = tid + p * 256;
        int r = idx >> 6;
        int c2 = (idx & 63) * 2;
        float v0 = red[r * HID + c2]     + red[(32 + r) * HID + c2]
                 + red[(64 + r) * HID + c2] + red[(96 + r) * HID + c2];
        float v1 = red[r * HID + c2 + 1] + red[(32 + r) * HID + c2 + 1]
                 + red[(64 + r) * HID + c2 + 1] + red[(96 + r) * HID + c2 + 1];
        union { bf16x2 h; unsigned int u; } cv;
        cv.h[0] = (__bf16)v0; cv.h[1] = (__bf16)v1;
        __builtin_nontemporal_store(cv.u,
            reinterpret_cast<unsigned int*>(pb + (size_t)(row_base + r) * HID + c2));
    }
}

// Fused: m = relu(sum partials + bmel) inline; x = relu([text|m]@Wcat + bcat);
// h1s = (x @ W1) * dinv -> bf16.
__global__ __launch_bounds__(256) void gemm_cat_h1(
    const float* __restrict__ A0,
    const __bf16* __restrict__ part,
    const float* __restrict__ bmel,
    const __bf16* __restrict__ Bf2,
    const __bf16* __restrict__ Bf3,
    const float* __restrict__ bcat,
    const float* __restrict__ dinv,
    __bf16* __restrict__ h1)
{
    const int tid = threadIdx.x;
    const int lane = tid & 63;
    const int w = tid >> 6;
    const int row_base = blockIdx.x * 32;
    const int rif = lane & 15;
    const int kg = lane >> 4;

    f32x4 zero = {0.f, 0.f, 0.f, 0.f};
    f32x4 acc[2][8];
#pragma unroll
    for (int i = 0; i < 2; ++i)
#pragma unroll
        for (int j = 0; j < 8; ++j) acc[i][j] = zero;

    const bf16x8* __restrict__ Bf2V = reinterpret_cast<const bf16x8*>(Bf2);
    const int kstart = w * 224;
    const size_t N = (size_t)20000 * HID;

#pragma unroll
    for (int it = 0; it < 7; ++it) {
        const int k0 = kstart + it * 32;
        const int kc = k0 + kg * 8;
        bf16x8 af[2];
#pragma unroll
        for (int mi = 0; mi < 2; ++mi) {
            const int row = row_base + mi * 16 + rif;
            if (k0 < 768) {
                const f32x4* apv = reinterpret_cast<const f32x4*>(A0 + (size_t)row * 768 + kc);
                f32x4 v0 = __builtin_nontemporal_load(apv);
                f32x4 v1 = __builtin_nontemporal_load(apv + 1);
                af[mi][0] = (__bf16)v0.x; af[mi][1] = (__bf16)v0.y;
                af[mi][2] = (__bf16)v0.z; af[mi][3] = (__bf16)v0.w;
                af[mi][4] = (__bf16)v1.x; af[mi][5] = (__bf16)v1.y;
                af[mi][6] = (__bf16)v1.z; af[mi][7] = (__bf16)v1.w;
            } else {
                const int mcol = kc - 768;
                const size_t base = (size_t)row * HID + mcol;
                bf16x8 q0 = *reinterpret_cast<const bf16x8*>(part + base);
                bf16x8 q1 = *reinterpret_cast<const bf16x8*>(part + N + base);
                bf16x8 q2 = *reinterpret_cast<const bf16x8*>(part + 2 * N + base);
                bf16x8 q3 = *reinterpret_cast<const bf16x8*>(part + 3 * N + base);
                const float* bp_ = bmel + mcol;
#pragma unroll
                for (int jj = 0; jj < 8; ++jj) {
                    float v = (float)q0[jj] + (float)q1[jj] + (float)q2[jj] + (float)q3[jj] + bp_[jj];
                    af[mi][jj] = (__bf16)fmaxf(v, 0.f);
                }
            }
        }
        const bf16x8* bp = Bf2V + (size_t)(k0 >> 5) * 512 + lane;
#pragma unroll
        for (int nf = 0; nf < 8; ++nf) {
            bf16x8 bq = bp[nf * 64];
            acc[0][nf] = __builtin_amdgcn_mfma_f32_16x16x32_bf16(af[0], bq, acc[0][nf], 0, 0, 0);
            acc[1][nf] = __builtin_amdgcn_mfma_f32_16x16x32_bf16(af[1], bq, acc[1][nf], 0, 0, 0);
        }
    }

    __shared__ float red[4][32][HID];
    __shared__ __bf16 xs[32][136];

#pragma unroll
    for (int mi = 0; mi < 2; ++mi)
#pragma unroll
        for (int nf = 0; nf < 8; ++nf)
#pragma unroll
            for (int j = 0; j < 4; ++j)
                red[w][mi * 16 + kg * 4 + j][nf * 16 + rif] = acc[mi][nf][j];
    __syncthreads();
#pragma unroll
    for (int p = 0; p < 16; ++p) {
        int idx = tid + p * 256;
        int r = idx >> 7, c = idx & 127;
        float v = red[0][r][c] + red[1][r][c] + red[2][r][c] + red[3][r][c];
        v = fmaxf(v + bcat[c], 0.f);
        xs[r][c] = (__bf16)v;
    }
    __syncthreads();

    f32x4 acc2[2][8];
#pragma unroll
    for (int i = 0; i < 2; ++i)
#pragma unroll
        for (int j = 0; j < 8; ++j) acc2[i][j] = zero;

    {
        const int k0 = w * 32;
        bf16x8 af[2];
#pragma unroll
        for (int mi = 0; mi < 2; ++mi)
            af[mi] = *reinterpret_cast<const bf16x8*>(&xs[mi * 16 + rif][k0 + kg * 8]);
        const bf16x8* bp = reinterpret_cast<const bf16x8*>(Bf3) + (size_t)w * 512 + lane;
#pragma unroll
        for (int nf = 0; nf < 8; ++nf) {
            bf16x8 bq = bp[nf * 64];
            acc2[0][nf] = __builtin_amdgcn_mfma_f32_16x16x32_bf16(af[0], bq, acc2[0][nf], 0, 0, 0);
            acc2[1][nf] = __builtin_amdgcn_mfma_f32_16x16x32_bf16(af[1], bq, acc2[1][nf], 0, 0, 0);
        }
    }

#pragma unroll
    for (int mi = 0; mi < 2; ++mi)
#pragma unroll
        for (int nf = 0; nf < 8; ++nf)
#pragma unroll
            for (int j = 0; j < 4; ++j)
                red[w][mi * 16 + kg * 4 + j][nf * 16 + rif] = acc2[mi][nf][j];
    __syncthreads();
#pragma unroll
    for (int p = 0; p < 16; ++p) {
        int idx = tid + p * 256;
        int r = idx >> 7, c = idx & 127;
        float v = red[0][r][c] + red[1][r][c] + red[2][r][c] + red[3][r][c];
        h1[(size_t)(row_base + r) * HID + c] = (__bf16)(v * dinv[row_base + r]);
    }
}

// scan: offs exclusive, offs[n]=E; dinv = rsqrt(deg+1)
__global__ __launch_bounds__(1024) void scan_block(const int* __restrict__ cnt,
    int* __restrict__ offs, float* __restrict__ dinv, int n) {
    int tid = threadIdx.x;
    int CH = (n + 1023) >> 10;
    int s0 = tid * CH;
    int s1 = min(s0 + CH, n);
    int sum = 0;
    for (int i = s0; i < s1; ++i) sum += cnt[i];
    int lane = tid & 63, wv = tid >> 6;
    int s = sum;
#pragma unroll
    for (int off = 1; off < 64; off <<= 1) {
        int t = __shfl_up(s, off);
        if (lane >= off) s += t;
    }
    __shared__ int wsum[16];
    __shared__ int wbase[16];
    if (lane == 63) wsum[wv] = s;
    __syncthreads();
    if (tid == 0) {
        int a = 0;
#pragma unroll
        for (int k = 0; k < 16; ++k) { wbase[k] = a; a += wsum[k]; }
        offs[n] = a;
    }
    __syncthreads();
    int run = wbase[wv] + (s - sum);
    for (int i = s0; i < s1; ++i) {
        int v = cnt[i];
        offs[i] = run;
        dinv[i] = rsqrtf((float)(v + 1));
        run += v;
    }
}

// h1s pre-scaled. yb = relu((h1s[i]+sum_s h1s[s])*di + b1); h2s = (yb@W2)*di.
__global__ __launch_bounds__(64) void agg_h_w2(const __bf16* __restrict__ hs,
    const float* __restrict__ dinv, const int* __restrict__ offs,
    const int* __restrict__ srcs,
    const float* __restrict__ b1, const float* __restrict__ W2,
    float* __restrict__ h2, int n) {
    int i = blockIdx.x;
    int c = threadIdx.x;
    float di = dinv[i];
    const int col = 2 * c;
    bf16x2 hv = *reinterpret_cast<const bf16x2*>(hs + (size_t)i * HID + col);
    float a0 = (float)hv[0];
    float a1 = (float)hv[1];
    int o = offs[i];
    int e = offs[i + 1] - o;
    int t = 0;
    for (; t + 8 <= e; t += 8) {
        int sx[8];
#pragma unroll
        for (int q = 0; q < 8; ++q) sx[q] = srcs[o + t + q];
        bf16x2 v[8];
#pragma unroll
        for (int q = 0; q < 8; ++q) v[q] = *reinterpret_cast<const bf16x2*>(hs + (size_t)sx[q] * HID + col);
#pragma unroll
        for (int q = 0; q < 8; ++q) { a0 += (float)v[q][0]; a1 += (float)v[q][1]; }
    }
    for (; t < e; ++t) {
        int s = srcs[o + t];
        bf16x2 v = *reinterpret_cast<const bf16x2*>(hs + (size_t)s * HID + col);
        a0 += (float)v[0];
        a1 += (float)v[1];
    }
    float yb0 = fmaxf(a0 * di + b1[col], 0.f);
    float yb1 = fmaxf(a1 * di + b1[col + 1], 0.f);
    float4 w0 = *reinterpret_cast<const float4*>(W2 + col * 4);
    float4 w1 = *reinterpret_cast<const float4*>(W2 + col * 4 + 4);
    float p0 = yb0 * w0.x + yb1 * w1.x;
    float p1 = yb0 * w0.y + yb1 * w1.y;
    float p2 = yb0 * w0.z + yb1 * w1.z;
    float p3 = yb0 * w0.w + yb1 * w1.w;
#pragma unroll
    for (int off = 32; off; off >>= 1) {
        p0 += __shfl_down(p0, off);
        p1 += __shfl_down(p1, off);
        p2 += __shfl_down(p2, off);
        p3 += __shfl_down(p3, off);
    }
    if (c == 0) {
        float4 r = {p0 * di, p1 * di, p2 * di, p3 * di};
        *reinterpret_cast<float4*>(h2 + (size_t)i * 4) = r;
    }
}

// out = (h2s[i] + sum_s h2s[s]) * di + b2
__global__ void agg4(const float* __restrict__ h2s, const float* __restrict__ dinv,
                     const int* __restrict__ offs,
                     const int* __restrict__ srcs, const float* __restrict__ b2,
                     float* __restrict__ out, int n) {
    int gid = blockIdx.x * 256 + threadIdx.x;
    int i = gid >> 2;
    int c = gid & 3;
    if (i >= n) return;
    float di = dinv[i];
    float acc = h2s[(size_t)i * 4 + c];
    int o = offs[i];
    int e = offs[i + 1] - o;
    int t = 0;
    for (; t + 4 <= e; t += 4) {
        int a0 = srcs[o + t], a1 = srcs[o + t + 1], a2 = srcs[o + t + 2], a3 = srcs[o + t + 3];
        acc += h2s[(size_t)a0 * 4 + c] + h2s[(size_t)a1 * 4 + c]
             + h2s[(size_t)a2 * 4 + c] + h2s[(size_t)a3 * 4 + c];
    }
    for (; t < e; ++t) {
        int s = srcs[o + t];
        acc += h2s[(size_t)s * 4 + c];
    }
    out[(size_t)i * 4 + c] = acc * di + b2[c];
}

extern "C" void kernel_launch(void* const* d_in, const int* in_sizes, int n_in,
                              void* d_out, int out_size, void* d_ws, size_t ws_size,
                              hipStream_t stream) {
    const float* text = (const float*)d_in[0];
    const float* mel  = (const float*)d_in[1];
    const int*   ei   = (const int*)d_in[2];
    const float* Wmel = (const float*)d_in[3];
    const float* bmel = (const float*)d_in[4];
    const float* Wcat = (const float*)d_in[5];
    const float* bcat = (const float*)d_in[6];
    const float* W1   = (const float*)d_in[7];
    const float* b1   = (const float*)d_in[8];
    const float* W2   = (const float*)d_in[9];
    const float* b2   = (const float*)d_in[10];
    float* out = (float*)d_out;

    const int n = in_sizes[0] / 768;   // 20000
    const int E = in_sizes[2] / 2;     // 640000
    const int Kmel = 16384;

    char* ws = (char*)d_ws;
    size_t off = 0;
    auto alloc = [&](size_t bytes) {
        void* p = ws + off;
        off += (bytes + 255) & ~(size_t)255;
        return p;
    };
    __bf16* Bf1 = (__bf16*)alloc((size_t)Kmel * HID * 2);
    __bf16* Bf2 = (__bf16*)alloc((size_t)896 * HID * 2);
    __bf16* Bf3 = (__bf16*)alloc((size_t)HID * HID * 2);
    __bf16* part = (__bf16*)alloc((size_t)4 * n * HID * 2);
    __bf16* h1  = (__bf16*)alloc((size_t)n * HID * 2);
    float* h2   = (float*)alloc((size_t)n * 4 * 4);
    int* cnt    = (int*)alloc((size_t)n * 4);
    int* offs   = (int*)alloc((size_t)(n + 1) * 4);
    float* dinv = (float*)alloc((size_t)n * 4);
    int* srcs   = (int*)alloc((size_t)E * 4);
    (void)ws_size; (void)n_in; (void)out_size;

    const int* srcI = ei;
    const int* dstI = ei + E;

    // degrees + weight pack (fused, one launch)
    (void)hipMemsetAsync(cnt, 0, n * 4, stream);
    count_pack<<<1344, 256, 0, stream>>>(dstI, cnt, E, Wmel, Wcat, W1, Bf1, Bf2, Bf3);
    // prefix sums + dinv
    scan_block<<<1, 1024, 0, stream>>>(cnt, offs, dinv, n);
    // mel GEMM with CSR-fill blocks interleaved (fill hides in mel's HBM-bound run)
    gemm_mel_fill<<<2750, 256, 0, stream>>>(mel, Bf1, part, srcI, dstI, offs, cnt, srcs, E);
    // fused combine+cat: x = relu([text|relu(sum parts+bmel)]@Wcat+bcat); h1s=(x@W1)*dinv
    gemm_cat_h1<<<n / 32, 256, 0, stream>>>(text, part, bmel, Bf2, Bf3, bcat, dinv, h1);
    // h2s = relu(agg(h1s)+b1) @ W2 * dinv
    agg_h_w2<<<n, 64, 0, stream>>>(h1, dinv, offs, srcs, b1, W2, h2, n);
    // out = agg(h2s) + b2
    agg4<<<(n * 4 + 255) / 256, 256, 0, stream>>>(h2, dinv, offs, srcs, b2, out, n);
}